// Round 3
// baseline (772.412 us; speedup 1.0000x reference)
//
#include <hip/hip_runtime.h>
#include <hip/hip_bf16.h>

// Problem constants (shapes fixed by setup_inputs). All float I/O is fp32
// (established round 4: hardcoded-bf16 reads NaN'd twice; flag-version passed).
#define F_IN  500
#define HC    128   // H*C
#define NHEAD 8
#define CDIM  16
#define NCLS  16
#define KPAD  512   // F_IN padded to multiple of 32 for MFMA K-loop

static __device__ __forceinline__ float bf(const __hip_bfloat16 v) {
    return __bfloat162float(v);
}

// ordered-uint encoding for float atomicMax
static __device__ __forceinline__ unsigned int enc_f32(float f) {
    unsigned int u = __float_as_uint(f);
    return (u & 0x80000000u) ? ~u : (u | 0x80000000u);
}
static __device__ __forceinline__ float dec_f32(unsigned int u) {
    return __uint_as_float((u & 0x80000000u) ? (u & 0x7FFFFFFFu) : ~u);
}

typedef __bf16 bf16x8 __attribute__((ext_vector_type(8)));
typedef float f32x4 __attribute__((ext_vector_type(4)));

// ---------------------------------------------------------------- prep:
// transpose W1 -> split-bf16 W1^T (ids < 128*512) AND zero the int region
// (deg/start/cursor/gmax = 3N+96 ints) in one launch.
__global__ void prep_kernel(const float* __restrict__ W1,
                            __bf16* __restrict__ w1t_hi,
                            __bf16* __restrict__ w1t_lo,
                            int* __restrict__ zp, int nz)
{
    int id = blockIdx.x * 256 + threadIdx.x;
    if (id < HC * KPAD) {
        int c = id >> 9, k = id & 511;
        float v = (k < F_IN) ? W1[k * HC + c] : 0.f;
        __bf16 h = (__bf16)v;
        w1t_hi[id] = h;
        w1t_lo[id] = (__bf16)(v - (float)h);
    }
    if (id < nz) zp[id] = 0;
}

// split 8 fp32 into bf16 hi + bf16 lo fragments
static __device__ __forceinline__ void split8(const float4 a, const float4 b,
                                              bf16x8& hi, bf16x8& lo) {
    float v[8] = {a.x, a.y, a.z, a.w, b.x, b.y, b.z, b.w};
#pragma unroll
    for (int j = 0; j < 8; j++) {
        __bf16 h = (__bf16)v[j];
        hi[j] = h;
        lo[j] = (__bf16)(v[j] - (float)h);
    }
}

// ---------------------------------------------------------------- GEMM1 v4 (MFMA, split-bf16):
// h1 = x @ W1 -> bf16 [N,128]. Block tile 64 rows x 128 cols, BK=32, 16 K-steps.
// 4 waves: wave (wr,wc) owns rows [wr*32,+32) x cols [wc*64,+64).
//  - B (w1t hi/lo, 256KB L2-hot) loaded DIRECTLY to registers in MFMA fragment
//    layout (16 cols x 64B segments per load = native L2 granules). No LDS.
//  - A reg-staged (T14): global->reg (2x float4, 128B/row contiguous) ->
//    swizzled ds_write -> single raw s_barrier + lgkmcnt(0) per K-step.
//    No global_load_lds => no conservative LDS-DMA vmcnt(0) drains; the
//    backend emits precise counts and A(t+2)/B prefetches stay in flight.
//  - LDS 16KB (2x 8KB A buffers) + launch_bounds(256,4) => 4 blocks/CU.
// Single-barrier ping-pong correctness: buffer b is read in iter t and written
// in iter t+1; lgkmcnt(0)+s_barrier at end of each iter separates them.
// Swizzle: A physslot = logslot ^ (row&7) (16B units), applied at ds_write and
// ds_read (both-sides, rule #21 n/a since no DMA).
// acc += Ah*Bh + Ah*Bl + Al*Bh  (identical numerics/order to v2/v3).
__global__ __launch_bounds__(256, 4) void gemm1_v4(
    const float* __restrict__ x,
    const __bf16* __restrict__ w1hi, const __bf16* __restrict__ w1lo,
    __hip_bfloat16* __restrict__ h1, int N)
{
    __shared__ float As[2][64 * 32];   // 2 x 8KB

    const int tid = threadIdx.x;
    const int lane = tid & 63, wave = tid >> 6;
    const int m = lane & 15, q = lane >> 4;
    const int wr = wave >> 1, wc = wave & 1;
    const int n0 = blockIdx.x * 64;

    // A staging: thread -> row sr = tid>>2, chunk sp = tid&3 (8 consecutive floats)
    const int sr = tid >> 2, sp = tid & 3;
    long arow = n0 + sr; if (arow >= N) arow = 0;
    const float* aptr = x + arow * F_IN + sp * 8;

    // B fragment bases (per-lane): col = wc*64 + ct*16 + m, k-slice q*8
    const __bf16* bhb = w1hi + (size_t)(wc * 64 + m) * KPAD + q * 8;
    const __bf16* blb = w1lo + (size_t)(wc * 64 + m) * KPAD + q * 8;

    f32x4 acc[2][4];
#pragma unroll
    for (int rt = 0; rt < 2; ++rt)
#pragma unroll
        for (int ct = 0; ct < 4; ++ct) acc[rt][ct] = (f32x4){0.f, 0.f, 0.f, 0.f};

    // prologue: stage A(0) into buf 0; preload A(1) into regs
    float4 nxt0, nxt1;
    {
        float4 c0 = *(const float4*)(aptr);
        float4 c1 = *(const float4*)(aptr + 4);
        float4* dst = (float4*)&As[0][sr * 32];
        dst[(2 * sp) ^ (sr & 7)] = c0;
        dst[(2 * sp + 1) ^ (sr & 7)] = c1;
        nxt0 = *(const float4*)(aptr + 32);
        nxt1 = *(const float4*)(aptr + 36);
        asm volatile("s_waitcnt lgkmcnt(0)" ::: "memory");
        __builtin_amdgcn_s_barrier();
    }

#pragma unroll
    for (int t = 0; t < 16; ++t) {
        const int cur = t & 1;

        // A fragments from LDS buf[cur]
        bf16x8 ah[2], al[2];
#pragma unroll
        for (int rt = 0; rt < 2; ++rt) {
            int r = wr * 32 + rt * 16 + m;
            int x7 = r & 7;
            const float4* rowp = (const float4*)&As[cur][r * 32];
            float4 f0 = rowp[(2 * q) ^ x7];
            float4 f1 = rowp[(2 * q + 1) ^ x7];
            split8(f0, f1, ah[rt], al[rt]);
        }
        // B fragments direct from global (L2-resident, fragment-native layout)
        bf16x8 bh[4], bl[4];
#pragma unroll
        for (int ct = 0; ct < 4; ++ct) {
            bh[ct] = *(const bf16x8*)(bhb + ct * 16 * KPAD + t * 32);
            bl[ct] = *(const bf16x8*)(blb + ct * 16 * KPAD + t * 32);
        }
        // prefetch A(t+2) -> regs (t==13 loads the guarded tail chunk t=15)
        float4 fut0 = make_float4(0.f, 0.f, 0.f, 0.f);
        float4 fut1 = make_float4(0.f, 0.f, 0.f, 0.f);
        if (t < 13) {
            fut0 = *(const float4*)(aptr + (t + 2) * 32);
            fut1 = *(const float4*)(aptr + (t + 2) * 32 + 4);
        } else if (t == 13) {
            float v[8];
#pragma unroll
            for (int j = 0; j < 8; j++) {
                int k = 15 * 32 + sp * 8 + j;          // 480 + sp*8 + j
                v[j] = (k < F_IN) ? aptr[15 * 32 + j] : 0.f;
            }
            fut0 = make_float4(v[0], v[1], v[2], v[3]);
            fut1 = make_float4(v[4], v[5], v[6], v[7]);
        }
        // stage A(t+1) into the other buffer (its readers finished last iter)
        if (t < 15) {
            float4* dst = (float4*)&As[cur ^ 1][sr * 32];
            dst[(2 * sp) ^ (sr & 7)] = nxt0;
            dst[(2 * sp + 1) ^ (sr & 7)] = nxt1;
        }

        __builtin_amdgcn_s_setprio(1);
#pragma unroll
        for (int rt = 0; rt < 2; ++rt)
#pragma unroll
            for (int ct = 0; ct < 4; ++ct) {
                acc[rt][ct] = __builtin_amdgcn_mfma_f32_16x16x32_bf16(ah[rt], bh[ct], acc[rt][ct], 0, 0, 0);
                acc[rt][ct] = __builtin_amdgcn_mfma_f32_16x16x32_bf16(ah[rt], bl[ct], acc[rt][ct], 0, 0, 0);
                acc[rt][ct] = __builtin_amdgcn_mfma_f32_16x16x32_bf16(al[rt], bh[ct], acc[rt][ct], 0, 0, 0);
            }
        __builtin_amdgcn_s_setprio(0);

        if (t < 15) {
            asm volatile("s_waitcnt lgkmcnt(0)" ::: "memory");  // reads+writes done
            __builtin_amdgcn_s_barrier();
        }
        nxt0 = fut0; nxt1 = fut1;
    }

    // store: C/D layout col=lane&15, row=(lane>>4)*4+reg
#pragma unroll
    for (int rt = 0; rt < 2; ++rt) {
        int rbase = n0 + wr * 32 + rt * 16 + q * 4;
#pragma unroll
        for (int ct = 0; ct < 4; ++ct) {
            int col = wc * 64 + ct * 16 + m;
#pragma unroll
            for (int r = 0; r < 4; ++r) {
                int row = rbase + r;
                if (row < N)
                    h1[(size_t)row * HC + col] = __float2bfloat16(acc[rt][ct][r]);
            }
        }
    }
}

// ---------------------------------------------------------------- per-node attention dots for layer 1
// d1[j*N*8 + n*8 + h] = sum_c h1[n,h,c] * a1[j,h,c]; fused per-head global max
// of d1m/d1t (replaces maxred_d1).
__global__ void dots1_kernel(const __hip_bfloat16* __restrict__ h1,
                             const float* __restrict__ a1,
                             float* __restrict__ d1,
                             unsigned int* __restrict__ gmax, int N)
{
    __shared__ unsigned int sm[16];
    if (threadIdx.x < 16) sm[threadIdx.x] = 0;
    __syncthreads();
    int id = blockIdx.x * blockDim.x + threadIdx.x;
    if (id < N * NHEAD) {
        int n = id >> 3, h = id & 7;
        const __hip_bfloat16* hp = h1 + (size_t)n * HC + h * CDIM;
        float s0 = 0.f, s1 = 0.f, s2 = 0.f;
#pragma unroll
        for (int c = 0; c < CDIM; c++) {
            float v = bf(hp[c]);
            s0 += v * a1[(0 * NHEAD + h) * CDIM + c];
            s1 += v * a1[(1 * NHEAD + h) * CDIM + c];
            s2 += v * a1[(2 * NHEAD + h) * CDIM + c];
        }
        d1[id] = s0;
        d1[N * NHEAD + id] = s1;
        d1[2 * N * NHEAD + id] = s2;
        atomicMax(&sm[h], enc_f32(s1));
        atomicMax(&sm[8 + h], enc_f32(s2));
    }
    __syncthreads();
    if (threadIdx.x < 16) atomicMax(&gmax[threadIdx.x], sm[threadIdx.x]);
}

// ---------------------------------------------------------------- CSR build
__global__ void hist_kernel(const int* __restrict__ pidx, int* __restrict__ deg, int P) {
    int p = blockIdx.x * blockDim.x + threadIdx.x;
    if (p < P) atomicAdd(deg + pidx[p], 1);
}

__global__ void scan1_kernel(const int* __restrict__ deg, int* __restrict__ start,
                             int* __restrict__ bsum, int N) {
    __shared__ int sh[256];
    int i = blockIdx.x * 256 + threadIdx.x;
    int v = (i < N) ? deg[i] : 0;
    sh[threadIdx.x] = v;
    __syncthreads();
#pragma unroll
    for (int off = 1; off < 256; off <<= 1) {
        int x = (threadIdx.x >= off) ? sh[threadIdx.x - off] : 0;
        __syncthreads();
        sh[threadIdx.x] += x;
        __syncthreads();
    }
    if (i < N) start[i] = sh[threadIdx.x] - v;   // exclusive
    if (threadIdx.x == 255) bsum[blockIdx.x] = sh[255];
}

__global__ void scan2_kernel(int* __restrict__ bsum, int nb) {
    __shared__ int sh[512];
    int v = (threadIdx.x < nb) ? bsum[threadIdx.x] : 0;
    sh[threadIdx.x] = v;
    __syncthreads();
#pragma unroll
    for (int off = 1; off < 512; off <<= 1) {
        int x = (threadIdx.x >= off) ? sh[threadIdx.x - off] : 0;
        __syncthreads();
        sh[threadIdx.x] += x;
        __syncthreads();
    }
    if (threadIdx.x < nb) bsum[threadIdx.x] = sh[threadIdx.x] - v;  // exclusive
}

__global__ void scan3_kernel(int* __restrict__ start, const int* __restrict__ bsum, int N) {
    int i = blockIdx.x * 256 + threadIdx.x;
    if (i < N) start[i] += bsum[blockIdx.x];
}

__global__ void scatter_kernel(const int* __restrict__ pidx,
                               const int* __restrict__ start,
                               int* __restrict__ cursor,
                               int* __restrict__ csr, int P) {
    int p = blockIdx.x * blockDim.x + threadIdx.x;
    if (p >= P) return;
    int hd = pidx[p];
    int pos = atomicAdd(cursor + hd, 1);
    csr[start[hd] + pos] = p;
}

// ---------------------------------------------------------------- layer1 attention, CSR, single pass.
// One wave per node. Softmax shift = upper bound leaky(dh + gm[h] + gt[h])
// (monotone leaky => bounds every path logit; softmax invariant to shift).
// Inner gather loop: compile-time-unrolled fast path when a full group of 8
// is present (common: deg~Poisson(10)); runtime-bounded tail otherwise
// (identical summation order => bit-identical).
__global__ __launch_bounds__(256) void attn1_csr_kernel(
    const int* __restrict__ csr, const int* __restrict__ start,
    const int* __restrict__ deg, const int* __restrict__ pidx,
    const float* __restrict__ d1, const __hip_bfloat16* __restrict__ h1,
    const float* __restrict__ b1, const unsigned int* __restrict__ gmax,
    float* __restrict__ elu_out, int N, int P)
{
    int node = blockIdx.x * 4 + (threadIdx.x >> 6);
    if (node >= N) return;
    int lane = threadIdx.x & 63;
    int h = lane >> 3;
    int s0 = start[node], dg = deg[node];
    const float* d1m = d1 + (size_t)N * NHEAD;
    const float* d1t = d1 + (size_t)2 * N * NHEAD;
    const float dh = d1[node * NHEAD + h];
    float zub = dh + dec_f32(gmax[h]) + dec_f32(gmax[8 + h]);
    const float mxub = zub > 0.f ? zub : 0.2f * zub;

    float acc0 = 0.f, acc1 = 0.f, den = 0.f;
    for (int k0 = 0; k0 < dg; k0 += 8) {
        int kk = k0 + (lane & 7);
        bool valid = kk < dg;
        int p = csr[s0 + (valid ? kk : dg - 1)];
        int mid = pidx[P + p], tl = pidx[2 * P + p];
        float z = dh + d1m[mid * NHEAD + h] + d1t[tl * NHEAD + h];
        float e = z > 0.f ? z : 0.2f * z;
        float ex = valid ? __expf(e - mxub) : 0.f;
        den += ex;
        int kmax = dg - k0; if (kmax > 8) kmax = 8;
        if (kmax == 8) {
#pragma unroll
            for (int dk = 0; dk < 8; dk++) {
                int tl_b = __shfl(tl, dk, 8);
                float ex_b = __shfl(ex, dk, 8);
                __hip_bfloat162 v = *(const __hip_bfloat162*)(h1 + (size_t)tl_b * HC + 2 * lane);
                acc0 += ex_b * bf(v.x);
                acc1 += ex_b * bf(v.y);
            }
        } else {
            for (int dk = 0; dk < kmax; dk++) {
                int tl_b = __shfl(tl, dk, 8);
                float ex_b = __shfl(ex, dk, 8);
                __hip_bfloat162 v = *(const __hip_bfloat162*)(h1 + (size_t)tl_b * HC + 2 * lane);
                acc0 += ex_b * bf(v.x);
                acc1 += ex_b * bf(v.y);
            }
        }
    }
#pragma unroll
    for (int w = 1; w < 8; w <<= 1) den += __shfl_xor(den, w, 8);

    float inv = 1.f / (den + 1e-16f);
    int j0 = 2 * lane;
    float v0 = acc0 * inv + b1[j0];
    float v1 = acc1 * inv + b1[j0 + 1];
    v0 = v0 > 0.f ? v0 : __expf(v0) - 1.f;
    v1 = v1 > 0.f ? v1 : __expf(v1) - 1.f;
    *(float2*)(elu_out + (size_t)node * HC + j0) = make_float2(v0, v1);
}

// ---------------------------------------------------------------- layer2 GEMM + dots: h2 = elu @ W2 ; d2[j,n] = h2[n,:]·a2[j]
// fused global max of d2m/d2t (replaces maxred_d2)
__global__ __launch_bounds__(256) void layer2_kernel(
    const float* __restrict__ elu, const float* __restrict__ W2,
    const float* __restrict__ a2,
    float* __restrict__ h2, float* __restrict__ d2,
    unsigned int* __restrict__ gmax2, int N)
{
    __shared__ float rows[16][HC + 1];
    __shared__ float h2s[16][NCLS + 1];
    __shared__ unsigned int smax[2];
    const int n0 = blockIdx.x * 16;
    const int tid = threadIdx.x;
    if (tid < 2) smax[tid] = 0;
    for (int idx = tid; idx < 16 * HC; idx += 256) {
        int r = idx >> 7, c = idx & 127;
        rows[r][c] = (n0 + r < N) ? elu[(size_t)(n0 + r) * HC + c] : 0.f;
    }
    __syncthreads();
    int ln = tid >> 4, c = tid & 15;
    float acc = 0.f;
#pragma unroll 8
    for (int j = 0; j < HC; j++) acc += rows[ln][j] * W2[j * NCLS + c];
    h2s[ln][c] = acc;
    if (n0 + ln < N) h2[(size_t)(n0 + ln) * NCLS + c] = acc;
    __syncthreads();
    if (tid < 48) {
        int l = tid / 3, j = tid - l * 3;
        if (n0 + l < N) {
            float s = 0.f;
#pragma unroll
            for (int cc = 0; cc < NCLS; cc++) s += h2s[l][cc] * a2[j * NCLS + cc];
            d2[j * N + n0 + l] = s;
            if (j) atomicMax(&smax[j - 1], enc_f32(s));
        }
    }
    __syncthreads();
    if (tid < 2) atomicMax(&gmax2[tid], smax[tid]);
}

// ---------------------------------------------------------------- layer2 attention CSR, single pass + log_softmax -> out (fp32)
// Fast-path unroll-16 when a full group is present; runtime tail otherwise.
__global__ __launch_bounds__(256) void attn2_csr_kernel(
    const int* __restrict__ csr, const int* __restrict__ start,
    const int* __restrict__ deg, const int* __restrict__ pidx,
    const float* __restrict__ d2, const float* __restrict__ h2,
    const float* __restrict__ b2, const unsigned int* __restrict__ gmax2,
    float* __restrict__ out, int N, int P)
{
    int node = blockIdx.x * 16 + (threadIdx.x >> 4);
    if (node >= N) return;
    int c = threadIdx.x & 15;
    int s0 = start[node], dg = deg[node];
    const float dh = d2[node];
    const float* d2m = d2 + N;
    const float* d2t = d2 + 2 * N;
    float zub = dh + dec_f32(gmax2[0]) + dec_f32(gmax2[1]);
    const float mxub = zub > 0.f ? zub : 0.2f * zub;

    float acc = 0.f, den = 0.f;
    for (int k0 = 0; k0 < dg; k0 += 16) {
        int kk = k0 + c;
        bool valid = kk < dg;
        int p = csr[s0 + (valid ? kk : dg - 1)];
        int mid = pidx[P + p], tl = pidx[2 * P + p];
        float z = dh + d2m[mid] + d2t[tl];
        float e = z > 0.f ? z : 0.2f * z;
        float ex = valid ? __expf(e - mxub) : 0.f;
        den += ex;
        int kmax = dg - k0; if (kmax > 16) kmax = 16;
        if (kmax == 16) {
#pragma unroll
            for (int dk = 0; dk < 16; dk++) {
                int tl_b = __shfl(tl, dk, 16);
                float ex_b = __shfl(ex, dk, 16);
                acc += ex_b * h2[(size_t)tl_b * NCLS + c];
            }
        } else {
            for (int dk = 0; dk < kmax; dk++) {
                int tl_b = __shfl(tl, dk, 16);
                float ex_b = __shfl(ex, dk, 16);
                acc += ex_b * h2[(size_t)tl_b * NCLS + c];
            }
        }
    }
#pragma unroll
    for (int w = 1; w < 16; w <<= 1) den += __shfl_xor(den, w, 16);

    float o = acc / (den + 1e-16f) + b2[c];
    // log_softmax across the 16 lanes of this node
    float m2 = o;
#pragma unroll
    for (int w = 1; w < 16; w <<= 1) m2 = fmaxf(m2, __shfl_xor(m2, w, 16));
    float ex = __expf(o - m2), sm = ex;
#pragma unroll
    for (int w = 1; w < 16; w <<= 1) sm += __shfl_xor(sm, w, 16);
    float r = o - m2 - __logf(sm);
    out[(size_t)node * NCLS + c] = r;
}

// ================================================================ launch
extern "C" void kernel_launch(void* const* d_in, const int* in_sizes, int n_in,
                              void* d_out, int out_size, void* d_ws, size_t ws_size,
                              hipStream_t stream)
{
    const float* x  = (const float*)d_in[0];
    const int*   pi = (const int*)d_in[1];
    const float* W1 = (const float*)d_in[2];
    const float* a1 = (const float*)d_in[3];
    const float* b1 = (const float*)d_in[4];
    const float* W2 = (const float*)d_in[5];
    const float* a2 = (const float*)d_in[6];
    const float* b2 = (const float*)d_in[7];

    const int N = in_sizes[0] / F_IN;   // 100000
    const int P = in_sizes[1] / 3;      // 1000000

    float* ws = (float*)d_ws;
    // workspace (float units): peak ~238N + P + 68k floats (~99.5 MB)
    size_t off_h1     = 0;                          // 64N  (bf16 x 128N)
    size_t off_d1     = (size_t)64 * N;             // 24N
    size_t off_elu    = (size_t)88 * N;             // 128N
    size_t off_h2     = (size_t)216 * N;            // 16N
    size_t off_d2     = (size_t)232 * N;            // 3N
    size_t off_deg    = (size_t)235 * N;            // N (int)
    size_t off_start  = (size_t)236 * N;            // N (int)
    size_t off_cursor = (size_t)237 * N;            // N (int)
    size_t off_gmax   = (size_t)238 * N;            // 32 (uint: 16 for d1, 2 for d2)
    size_t off_bsum   = (size_t)238 * N + 96;       // 1024 (int)
    size_t off_csr    = (size_t)238 * N + 96 + 1024; // P (int)
    size_t off_w1th   = off_csr + P;                // 32768 (bf16 x 65536)
    size_t off_w1tl   = off_w1th + 32768;           // 32768

    __hip_bfloat16* h1 = (__hip_bfloat16*)(ws + off_h1);
    float* d1   = ws + off_d1;
    float* elu  = ws + off_elu;
    float* h2   = ws + off_h2;
    float* d2   = ws + off_d2;
    int* deg    = (int*)(ws + off_deg);
    int* start  = (int*)(ws + off_start);
    int* cursor = (int*)(ws + off_cursor);
    unsigned int* gmax  = (unsigned int*)(ws + off_gmax);       // 16
    unsigned int* gmax2 = (unsigned int*)(ws + off_gmax) + 16;  // 2
    int* bsum   = (int*)(ws + off_bsum);
    int* csr    = (int*)(ws + off_csr);
    __bf16* w1t_hi = (__bf16*)(ws + off_w1th);
    __bf16* w1t_lo = (__bf16*)(ws + off_w1tl);

    const int BLK = 256;
    const int nb = (N + 255) / 256;   // scan blocks (<= 512)
    const int nz = 3 * N + 96;        // deg..gmax zero region

    prep_kernel<<<(nz + 255) / 256, 256, 0, stream>>>(W1, w1t_hi, w1t_lo, deg, nz);
    gemm1_v4<<<(N + 63) / 64, 256, 0, stream>>>(x, w1t_hi, w1t_lo, h1, N);
    dots1_kernel<<<(N * NHEAD + BLK - 1) / BLK, BLK, 0, stream>>>(h1, a1, d1, gmax, N);
    // CSR build
    hist_kernel<<<(P + BLK - 1) / BLK, BLK, 0, stream>>>(pi, deg, P);
    scan1_kernel<<<nb, 256, 0, stream>>>(deg, start, bsum, N);
    scan2_kernel<<<1, 512, 0, stream>>>(bsum, nb);
    scan3_kernel<<<nb, 256, 0, stream>>>(start, bsum, N);
    scatter_kernel<<<(P + BLK - 1) / BLK, BLK, 0, stream>>>(pi, start, cursor, csr, P);
    // layer 1 attention (single-pass, fused softmax/aggregate/bias/elu)
    attn1_csr_kernel<<<(N + 3) / 4, 256, 0, stream>>>(csr, start, deg, pi, d1, h1, b1, gmax, elu, N, P);
    // layer 2
    layer2_kernel<<<(N + 15) / 16, 256, 0, stream>>>(elu, W2, a2, h2, d2, gmax2, N);
    attn2_csr_kernel<<<(N + 15) / 16, 256, 0, stream>>>(csr, start, deg, pi, d2, h2, b2, gmax2,
                                                        (float*)d_out, N, P);
}

// Round 4
// 727.939 us; speedup vs baseline: 1.0611x; 1.0611x over previous
//
#include <hip/hip_runtime.h>
#include <hip/hip_bf16.h>

// Problem constants (shapes fixed by setup_inputs). All float I/O is fp32
// (established round 4: hardcoded-bf16 reads NaN'd twice; flag-version passed).
#define F_IN  500
#define HC    128   // H*C
#define NHEAD 8
#define CDIM  16
#define NCLS  16
#define KPAD  512   // F_IN padded to multiple of 32 for MFMA K-loop

static __device__ __forceinline__ float bf(const __hip_bfloat16 v) {
    return __bfloat162float(v);
}

// ordered-uint encoding for float atomicMax
static __device__ __forceinline__ unsigned int enc_f32(float f) {
    unsigned int u = __float_as_uint(f);
    return (u & 0x80000000u) ? ~u : (u | 0x80000000u);
}
static __device__ __forceinline__ float dec_f32(unsigned int u) {
    return __uint_as_float((u & 0x80000000u) ? (u & 0x7FFFFFFFu) : ~u);
}

typedef __bf16 bf16x8 __attribute__((ext_vector_type(8)));
typedef float f32x4 __attribute__((ext_vector_type(4)));

// async global->LDS, 16B per lane. LDS dest = wave-uniform base + lane*16.
static __device__ __forceinline__ void gload16(const void* g, void* l) {
    __builtin_amdgcn_global_load_lds(
        (const __attribute__((address_space(1))) void*)g,
        (__attribute__((address_space(3))) void*)l, 16, 0, 0);
}

// 32-bit LDS byte offset of a shared-memory pointer
static __device__ __forceinline__ unsigned ldsoff(const void* p) {
    return (unsigned)(size_t)(const __attribute__((address_space(3))) void*)p;
}

// opaque LDS reads (invisible to the waitcnt pass -> no conservative
// vmcnt(0) drain for LDS-DMA aliasing; we do our own counted waits)
static __device__ __forceinline__ void ds_read_f4(unsigned addr, float4& out) {
    asm volatile("ds_read_b128 %0, %1" : "=v"(out) : "v"(addr) : "memory");
}
static __device__ __forceinline__ void ds_read_bf8(unsigned addr, bf16x8& out) {
    asm volatile("ds_read_b128 %0, %1" : "=v"(out) : "v"(addr) : "memory");
}

// ---------------------------------------------------------------- prep:
// transpose W1 -> split-bf16 W1^T (ids < 128*512) AND zero the int region
// (deg/start/cursor/gmax/zpad = 3N+96 ints) in one launch.
__global__ void prep_kernel(const float* __restrict__ W1,
                            __bf16* __restrict__ w1t_hi,
                            __bf16* __restrict__ w1t_lo,
                            int* __restrict__ zp, int nz)
{
    int id = blockIdx.x * 256 + threadIdx.x;
    if (id < HC * KPAD) {
        int c = id >> 9, k = id & 511;
        float v = (k < F_IN) ? W1[k * HC + c] : 0.f;
        __bf16 h = (__bf16)v;
        w1t_hi[id] = h;
        w1t_lo[id] = (__bf16)(v - (float)h);
    }
    if (id < nz) zp[id] = 0;
}

// split 8 fp32 into bf16 hi + bf16 lo fragments
static __device__ __forceinline__ void split8(const float4 a, const float4 b,
                                              bf16x8& hi, bf16x8& lo) {
    float v[8] = {a.x, a.y, a.z, a.w, b.x, b.y, b.z, b.w};
#pragma unroll
    for (int j = 0; j < 8; j++) {
        __bf16 h = (__bf16)v[j];
        hi[j] = h;
        lo[j] = (__bf16)(v[j] - (float)h);
    }
}

// ---------------------------------------------------------------- GEMM1 v5 (MFMA, split-bf16,
// 3-buffer LDS pipeline, counted vmcnt, INLINE-ASM fragment reads):
// h1 = x @ W1 -> bf16 [N,128]. Block tile 64 rows x 128 cols, BK=32, 16 K-steps.
// Identical structure/numerics to v3; the only change is that the LDS
// fragment reads are inline-asm ds_read_b128 + lgkmcnt(0) + sched_barrier(0)
// (rule #18), so the waitcnt pass cannot see an LDS read that may-alias the
// outstanding global_load_lds DMA writes and cannot insert a vmcnt(0) drain.
// Our counted vmcnt(12) (= 6 loads x 2 tiles in flight) is then the only
// vmem wait in the loop -- loads genuinely cross barriers (T3+T4).
__global__ __launch_bounds__(256, 2) void gemm1_v5(
    const float* __restrict__ x,
    const __bf16* __restrict__ w1hi, const __bf16* __restrict__ w1lo,
    const float* __restrict__ zpad,
    __hip_bfloat16* __restrict__ h1, int N)
{
    __shared__ float As[3][64 * 32];       // 24KB
    __shared__ __bf16 BsH[3][128 * 32];    // 24KB
    __shared__ __bf16 BsL[3][128 * 32];    // 24KB

    const int tid = threadIdx.x;
    const int lane = tid & 63, wave = tid >> 6;
    const int m = lane & 15, q = lane >> 4;
    const int wr = wave >> 1, wc = wave & 1;
    const int n0 = blockIdx.x * 64;
    const int woff = wave << 10;           // wave-uniform LDS byte offset

    // stage K-chunk t into buffer buf (6 x global_load_lds per thread)
    auto stage = [&](int buf, int t) {
        const int k0 = t * 32;
#pragma unroll
        for (int j = 0; j < 2; ++j) {
            int idx = j * 256 + tid;
            {   // A: row = idx>>3, 8 slots of 16B per row, swizzled source
                int r = idx >> 3, ps = idx & 7;
                int ls = ps ^ (r & 7);
                int kk = k0 + ls * 4;
                int grow = n0 + r;
                const float* src = (kk < F_IN)
                    ? (x + (size_t)(grow < N ? grow : 0) * F_IN + kk)
                    : zpad;
                gload16(src, (char*)&As[buf][0] + j * 4096 + woff);
            }
            {   // B hi/lo: col = idx>>2, 4 slots of 16B per col
                int c = idx >> 2, ps2 = idx & 3;
                int ls2 = ps2 ^ (c & 3);
                gload16(w1hi + c * KPAD + k0 + ls2 * 8, (char*)&BsH[buf][0] + j * 4096 + woff);
                gload16(w1lo + c * KPAD + k0 + ls2 * 8, (char*)&BsL[buf][0] + j * 4096 + woff);
            }
        }
    };

    // LDS base byte offsets (compile-time-known layout)
    unsigned abase[3], hbase[3], lbase[3];
#pragma unroll
    for (int i = 0; i < 3; ++i) {
        abase[i] = ldsoff(&As[i][0]);
        hbase[i] = ldsoff(&BsH[i][0]);
        lbase[i] = ldsoff(&BsL[i][0]);
    }
    // per-lane fragment byte offsets within a buffer
    unsigned aoffs[2][2], boffs[4];
#pragma unroll
    for (int rt = 0; rt < 2; ++rt) {
        int r = wr * 32 + rt * 16 + m, x7 = r & 7;
        aoffs[rt][0] = r * 128 + (((2 * q) ^ x7) << 4);
        aoffs[rt][1] = r * 128 + (((2 * q + 1) ^ x7) << 4);
    }
#pragma unroll
    for (int ct = 0; ct < 4; ++ct) {
        int c = wc * 64 + ct * 16 + m;
        boffs[ct] = c * 64 + ((q ^ (c & 3)) << 4);
    }

    f32x4 acc[2][4];
#pragma unroll
    for (int rt = 0; rt < 2; ++rt)
#pragma unroll
        for (int ct = 0; ct < 4; ++ct) acc[rt][ct] = (f32x4){0.f, 0.f, 0.f, 0.f};

    stage(0, 0);
    stage(1, 1);

#pragma unroll
    for (int t = 0; t < 16; ++t) {
        // separate compute(t-1) reads of buf[(t-1)%3] from stage writes to
        // buf[(t+2)%3] (same buffer)
        if (t > 0) __builtin_amdgcn_s_barrier();
        if (t + 2 < 16) stage((t + 2) % 3, t + 2);
        // wait for stage(t)'s 6 loads; keep up to 12 (tiles t+1,t+2) in flight
        if (t < 14)       asm volatile("s_waitcnt vmcnt(12)" ::: "memory");
        else if (t == 14) asm volatile("s_waitcnt vmcnt(6)" ::: "memory");
        else              asm volatile("s_waitcnt vmcnt(0)" ::: "memory");
        __builtin_amdgcn_s_barrier();

        const int cur = t % 3;
        // opaque fragment reads: 4x A (fp32x4 pairs), 8x B
        float4 fa[2][2];
        ds_read_f4(abase[cur] + aoffs[0][0], fa[0][0]);
        ds_read_f4(abase[cur] + aoffs[0][1], fa[0][1]);
        ds_read_f4(abase[cur] + aoffs[1][0], fa[1][0]);
        ds_read_f4(abase[cur] + aoffs[1][1], fa[1][1]);
        bf16x8 bh[4], bl[4];
#pragma unroll
        for (int ct = 0; ct < 4; ++ct) {
            ds_read_bf8(hbase[cur] + boffs[ct], bh[ct]);
            ds_read_bf8(lbase[cur] + boffs[ct], bl[ct]);
        }
        asm volatile("s_waitcnt lgkmcnt(0)" ::: "memory");
        __builtin_amdgcn_sched_barrier(0);   // rule #18: pin uses after the wait

        bf16x8 ah[2], al[2];
        split8(fa[0][0], fa[0][1], ah[0], al[0]);
        split8(fa[1][0], fa[1][1], ah[1], al[1]);

        __builtin_amdgcn_s_setprio(1);
#pragma unroll
        for (int rt = 0; rt < 2; ++rt)
#pragma unroll
            for (int ct = 0; ct < 4; ++ct) {
                acc[rt][ct] = __builtin_amdgcn_mfma_f32_16x16x32_bf16(ah[rt], bh[ct], acc[rt][ct], 0, 0, 0);
                acc[rt][ct] = __builtin_amdgcn_mfma_f32_16x16x32_bf16(ah[rt], bl[ct], acc[rt][ct], 0, 0, 0);
                acc[rt][ct] = __builtin_amdgcn_mfma_f32_16x16x32_bf16(al[rt], bh[ct], acc[rt][ct], 0, 0, 0);
            }
        __builtin_amdgcn_s_setprio(0);
    }

    // store: C/D layout col=lane&15, row=(lane>>4)*4+reg
#pragma unroll
    for (int rt = 0; rt < 2; ++rt) {
        int rbase = n0 + wr * 32 + rt * 16 + q * 4;
#pragma unroll
        for (int ct = 0; ct < 4; ++ct) {
            int col = wc * 64 + ct * 16 + m;
#pragma unroll
            for (int r = 0; r < 4; ++r) {
                int row = rbase + r;
                if (row < N)
                    h1[(size_t)row * HC + col] = __float2bfloat16(acc[rt][ct][r]);
            }
        }
    }
}

// ---------------------------------------------------------------- per-node attention dots for layer 1
// d1[j*N*8 + n*8 + h] = sum_c h1[n,h,c] * a1[j,h,c]; fused per-head global max
// of d1m/d1t (replaces maxred_d1).
__global__ void dots1_kernel(const __hip_bfloat16* __restrict__ h1,
                             const float* __restrict__ a1,
                             float* __restrict__ d1,
                             unsigned int* __restrict__ gmax, int N)
{
    __shared__ unsigned int sm[16];
    if (threadIdx.x < 16) sm[threadIdx.x] = 0;
    __syncthreads();
    int id = blockIdx.x * blockDim.x + threadIdx.x;
    if (id < N * NHEAD) {
        int n = id >> 3, h = id & 7;
        const __hip_bfloat16* hp = h1 + (size_t)n * HC + h * CDIM;
        float s0 = 0.f, s1 = 0.f, s2 = 0.f;
#pragma unroll
        for (int c = 0; c < CDIM; c++) {
            float v = bf(hp[c]);
            s0 += v * a1[(0 * NHEAD + h) * CDIM + c];
            s1 += v * a1[(1 * NHEAD + h) * CDIM + c];
            s2 += v * a1[(2 * NHEAD + h) * CDIM + c];
        }
        d1[id] = s0;
        d1[N * NHEAD + id] = s1;
        d1[2 * N * NHEAD + id] = s2;
        atomicMax(&sm[h], enc_f32(s1));
        atomicMax(&sm[8 + h], enc_f32(s2));
    }
    __syncthreads();
    if (threadIdx.x < 16) atomicMax(&gmax[threadIdx.x], sm[threadIdx.x]);
}

// ---------------------------------------------------------------- CSR build
__global__ void hist_kernel(const int* __restrict__ pidx, int* __restrict__ deg, int P) {
    int p = blockIdx.x * blockDim.x + threadIdx.x;
    if (p < P) atomicAdd(deg + pidx[p], 1);
}

__global__ void scan1_kernel(const int* __restrict__ deg, int* __restrict__ start,
                             int* __restrict__ bsum, int N) {
    __shared__ int sh[256];
    int i = blockIdx.x * 256 + threadIdx.x;
    int v = (i < N) ? deg[i] : 0;
    sh[threadIdx.x] = v;
    __syncthreads();
#pragma unroll
    for (int off = 1; off < 256; off <<= 1) {
        int x = (threadIdx.x >= off) ? sh[threadIdx.x - off] : 0;
        __syncthreads();
        sh[threadIdx.x] += x;
        __syncthreads();
    }
    if (i < N) start[i] = sh[threadIdx.x] - v;   // exclusive
    if (threadIdx.x == 255) bsum[blockIdx.x] = sh[255];
}

__global__ void scan2_kernel(int* __restrict__ bsum, int nb) {
    __shared__ int sh[512];
    int v = (threadIdx.x < nb) ? bsum[threadIdx.x] : 0;
    sh[threadIdx.x] = v;
    __syncthreads();
#pragma unroll
    for (int off = 1; off < 512; off <<= 1) {
        int x = (threadIdx.x >= off) ? sh[threadIdx.x - off] : 0;
        __syncthreads();
        sh[threadIdx.x] += x;
        __syncthreads();
    }
    if (threadIdx.x < nb) bsum[threadIdx.x] = sh[threadIdx.x] - v;  // exclusive
}

__global__ void scan3_kernel(int* __restrict__ start, const int* __restrict__ bsum, int N) {
    int i = blockIdx.x * 256 + threadIdx.x;
    if (i < N) start[i] += bsum[blockIdx.x];
}

__global__ void scatter_kernel(const int* __restrict__ pidx,
                               const int* __restrict__ start,
                               int* __restrict__ cursor,
                               int* __restrict__ csr, int P) {
    int p = blockIdx.x * blockDim.x + threadIdx.x;
    if (p >= P) return;
    int hd = pidx[p];
    int pos = atomicAdd(cursor + hd, 1);
    csr[start[hd] + pos] = p;
}

// ---------------------------------------------------------------- layer1 attention, CSR, single pass.
// One wave per node. Softmax shift = upper bound leaky(dh + gm[h] + gt[h])
// (monotone leaky => bounds every path logit; softmax invariant to shift).
// Inner loop runtime-bounded (measured best: predicated full-unroll cost +60%
// wasted gather traffic at deg~10 -- attn is gather-throughput bound).
__global__ __launch_bounds__(256) void attn1_csr_kernel(
    const int* __restrict__ csr, const int* __restrict__ start,
    const int* __restrict__ deg, const int* __restrict__ pidx,
    const float* __restrict__ d1, const __hip_bfloat16* __restrict__ h1,
    const float* __restrict__ b1, const unsigned int* __restrict__ gmax,
    float* __restrict__ elu_out, int N, int P)
{
    int node = blockIdx.x * 4 + (threadIdx.x >> 6);
    if (node >= N) return;
    int lane = threadIdx.x & 63;
    int h = lane >> 3;
    int s0 = start[node], dg = deg[node];
    const float* d1m = d1 + (size_t)N * NHEAD;
    const float* d1t = d1 + (size_t)2 * N * NHEAD;
    const float dh = d1[node * NHEAD + h];
    float zub = dh + dec_f32(gmax[h]) + dec_f32(gmax[8 + h]);
    const float mxub = zub > 0.f ? zub : 0.2f * zub;

    float acc0 = 0.f, acc1 = 0.f, den = 0.f;
    for (int k0 = 0; k0 < dg; k0 += 8) {
        int kk = k0 + (lane & 7);
        bool valid = kk < dg;
        int p = csr[s0 + (valid ? kk : dg - 1)];
        int mid = pidx[P + p], tl = pidx[2 * P + p];
        float z = dh + d1m[mid * NHEAD + h] + d1t[tl * NHEAD + h];
        float e = z > 0.f ? z : 0.2f * z;
        float ex = valid ? __expf(e - mxub) : 0.f;
        den += ex;
        int kmax = dg - k0; if (kmax > 8) kmax = 8;
        for (int dk = 0; dk < kmax; dk++) {
            int tl_b = __shfl(tl, dk, 8);
            float ex_b = __shfl(ex, dk, 8);
            __hip_bfloat162 v = *(const __hip_bfloat162*)(h1 + (size_t)tl_b * HC + 2 * lane);
            acc0 += ex_b * bf(v.x);
            acc1 += ex_b * bf(v.y);
        }
    }
#pragma unroll
    for (int w = 1; w < 8; w <<= 1) den += __shfl_xor(den, w, 8);

    float inv = 1.f / (den + 1e-16f);
    int j0 = 2 * lane;
    float v0 = acc0 * inv + b1[j0];
    float v1 = acc1 * inv + b1[j0 + 1];
    v0 = v0 > 0.f ? v0 : __expf(v0) - 1.f;
    v1 = v1 > 0.f ? v1 : __expf(v1) - 1.f;
    *(float2*)(elu_out + (size_t)node * HC + j0) = make_float2(v0, v1);
}

// ---------------------------------------------------------------- layer2 GEMM + dots: h2 = elu @ W2 ; d2[j,n] = h2[n,:]·a2[j]
// fused global max of d2m/d2t (replaces maxred_d2)
__global__ __launch_bounds__(256) void layer2_kernel(
    const float* __restrict__ elu, const float* __restrict__ W2,
    const float* __restrict__ a2,
    float* __restrict__ h2, float* __restrict__ d2,
    unsigned int* __restrict__ gmax2, int N)
{
    __shared__ float rows[16][HC + 1];
    __shared__ float h2s[16][NCLS + 1];
    __shared__ unsigned int smax[2];
    const int n0 = blockIdx.x * 16;
    const int tid = threadIdx.x;
    if (tid < 2) smax[tid] = 0;
    for (int idx = tid; idx < 16 * HC; idx += 256) {
        int r = idx >> 7, c = idx & 127;
        rows[r][c] = (n0 + r < N) ? elu[(size_t)(n0 + r) * HC + c] : 0.f;
    }
    __syncthreads();
    int ln = tid >> 4, c = tid & 15;
    float acc = 0.f;
#pragma unroll 8
    for (int j = 0; j < HC; j++) acc += rows[ln][j] * W2[j * NCLS + c];
    h2s[ln][c] = acc;
    if (n0 + ln < N) h2[(size_t)(n0 + ln) * NCLS + c] = acc;
    __syncthreads();
    if (tid < 48) {
        int l = tid / 3, j = tid - l * 3;
        if (n0 + l < N) {
            float s = 0.f;
#pragma unroll
            for (int cc = 0; cc < NCLS; cc++) s += h2s[l][cc] * a2[j * NCLS + cc];
            d2[j * N + n0 + l] = s;
            if (j) atomicMax(&smax[j - 1], enc_f32(s));
        }
    }
    __syncthreads();
    if (tid < 2) atomicMax(&gmax2[tid], smax[tid]);
}

// ---------------------------------------------------------------- layer2 attention CSR, single pass + log_softmax -> out (fp32)
__global__ __launch_bounds__(256) void attn2_csr_kernel(
    const int* __restrict__ csr, const int* __restrict__ start,
    const int* __restrict__ deg, const int* __restrict__ pidx,
    const float* __restrict__ d2, const float* __restrict__ h2,
    const float* __restrict__ b2, const unsigned int* __restrict__ gmax2,
    float* __restrict__ out, int N, int P)
{
    int node = blockIdx.x * 16 + (threadIdx.x >> 4);
    if (node >= N) return;
    int c = threadIdx.x & 15;
    int s0 = start[node], dg = deg[node];
    const float dh = d2[node];
    const float* d2m = d2 + N;
    const float* d2t = d2 + 2 * N;
    float zub = dh + dec_f32(gmax2[0]) + dec_f32(gmax2[1]);
    const float mxub = zub > 0.f ? zub : 0.2f * zub;

    float acc = 0.f, den = 0.f;
    for (int k0 = 0; k0 < dg; k0 += 16) {
        int kk = k0 + c;
        bool valid = kk < dg;
        int p = csr[s0 + (valid ? kk : dg - 1)];
        int mid = pidx[P + p], tl = pidx[2 * P + p];
        float z = dh + d2m[mid] + d2t[tl];
        float e = z > 0.f ? z : 0.2f * z;
        float ex = valid ? __expf(e - mxub) : 0.f;
        den += ex;
        int kmax = dg - k0; if (kmax > 16) kmax = 16;
        for (int dk = 0; dk < kmax; dk++) {
            int tl_b = __shfl(tl, dk, 16);
            float ex_b = __shfl(ex, dk, 16);
            acc += ex_b * h2[(size_t)tl_b * NCLS + c];
        }
    }
#pragma unroll
    for (int w = 1; w < 16; w <<= 1) den += __shfl_xor(den, w, 16);

    float o = acc / (den + 1e-16f) + b2[c];
    // log_softmax across the 16 lanes of this node
    float m2 = o;
#pragma unroll
    for (int w = 1; w < 16; w <<= 1) m2 = fmaxf(m2, __shfl_xor(m2, w, 16));
    float ex = __expf(o - m2), sm = ex;
#pragma unroll
    for (int w = 1; w < 16; w <<= 1) sm += __shfl_xor(sm, w, 16);
    float r = o - m2 - __logf(sm);
    out[(size_t)node * NCLS + c] = r;
}

// ================================================================ launch
extern "C" void kernel_launch(void* const* d_in, const int* in_sizes, int n_in,
                              void* d_out, int out_size, void* d_ws, size_t ws_size,
                              hipStream_t stream)
{
    const float* x  = (const float*)d_in[0];
    const int*   pi = (const int*)d_in[1];
    const float* W1 = (const float*)d_in[2];
    const float* a1 = (const float*)d_in[3];
    const float* b1 = (const float*)d_in[4];
    const float* W2 = (const float*)d_in[5];
    const float* a2 = (const float*)d_in[6];
    const float* b2 = (const float*)d_in[7];

    const int N = in_sizes[0] / F_IN;   // 100000
    const int P = in_sizes[1] / 3;      // 1000000

    float* ws = (float*)d_ws;
    // workspace (float units): peak ~238N + P + 68k floats (~99.5 MB)
    size_t off_h1     = 0;                          // 64N  (bf16 x 128N)
    size_t off_d1     = (size_t)64 * N;             // 24N
    size_t off_elu    = (size_t)88 * N;             // 128N
    size_t off_h2     = (size_t)216 * N;            // 16N
    size_t off_d2     = (size_t)232 * N;            // 3N
    size_t off_deg    = (size_t)235 * N;            // N (int)
    size_t off_start  = (size_t)236 * N;            // N (int)
    size_t off_cursor = (size_t)237 * N;            // N (int)
    size_t off_gmax   = (size_t)238 * N;            // 32 (uint: 16 for d1, 2 for d2)
    size_t off_zpad   = (size_t)238 * N + 32;       // 64 (float, zeroed; 16B-aligned pad for gemm1 k>=500)
    size_t off_bsum   = (size_t)238 * N + 96;       // 1024 (int)
    size_t off_csr    = (size_t)238 * N + 96 + 1024; // P (int)
    size_t off_w1th   = off_csr + P;                // 32768 (bf16 x 65536)
    size_t off_w1tl   = off_w1th + 32768;           // 32768

    __hip_bfloat16* h1 = (__hip_bfloat16*)(ws + off_h1);
    float* d1   = ws + off_d1;
    float* elu  = ws + off_elu;
    float* h2   = ws + off_h2;
    float* d2   = ws + off_d2;
    int* deg    = (int*)(ws + off_deg);
    int* start  = (int*)(ws + off_start);
    int* cursor = (int*)(ws + off_cursor);
    unsigned int* gmax  = (unsigned int*)(ws + off_gmax);       // 16
    unsigned int* gmax2 = (unsigned int*)(ws + off_gmax) + 16;  // 2
    float* zpad = ws + off_zpad;
    int* bsum   = (int*)(ws + off_bsum);
    int* csr    = (int*)(ws + off_csr);
    __bf16* w1t_hi = (__bf16*)(ws + off_w1th);
    __bf16* w1t_lo = (__bf16*)(ws + off_w1tl);

    const int BLK = 256;
    const int nb = (N + 255) / 256;   // scan blocks (<= 512)
    const int nz = 3 * N + 96;        // deg..zpad zero region

    prep_kernel<<<(nz + 255) / 256, 256, 0, stream>>>(W1, w1t_hi, w1t_lo, deg, nz);
    gemm1_v5<<<(N + 63) / 64, 256, 0, stream>>>(x, w1t_hi, w1t_lo, zpad, h1, N);
    dots1_kernel<<<(N * NHEAD + BLK - 1) / BLK, BLK, 0, stream>>>(h1, a1, d1, gmax, N);
    // CSR build
    hist_kernel<<<(P + BLK - 1) / BLK, BLK, 0, stream>>>(pi, deg, P);
    scan1_kernel<<<nb, 256, 0, stream>>>(deg, start, bsum, N);
    scan2_kernel<<<1, 512, 0, stream>>>(bsum, nb);
    scan3_kernel<<<nb, 256, 0, stream>>>(start, bsum, N);
    scatter_kernel<<<(P + BLK - 1) / BLK, BLK, 0, stream>>>(pi, start, cursor, csr, P);
    // layer 1 attention (single-pass, fused softmax/aggregate/bias/elu)
    attn1_csr_kernel<<<(N + 3) / 4, 256, 0, stream>>>(csr, start, deg, pi, d1, h1, b1, gmax, elu, N, P);
    // layer 2
    layer2_kernel<<<(N + 15) / 16, 256, 0, stream>>>(elu, W2, a2, h2, d2, gmax2, N);
    attn2_csr_kernel<<<(N + 15) / 16, 256, 0, stream>>>(csr, start, deg, pi, d2, h2, b2, gmax2,
                                                        (float*)d_out, N, P);
}

// Round 5
// 724.962 us; speedup vs baseline: 1.0655x; 1.0041x over previous
//
#include <hip/hip_runtime.h>
#include <hip/hip_bf16.h>

// Problem constants (shapes fixed by setup_inputs). All float I/O is fp32
// (established round 4: hardcoded-bf16 reads NaN'd twice; flag-version passed).
#define F_IN  500
#define HC    128   // H*C
#define NHEAD 8
#define CDIM  16
#define NCLS  16
#define KPAD  512   // F_IN padded to multiple of 32 for MFMA K-loop

static __device__ __forceinline__ float bf(const __hip_bfloat16 v) {
    return __bfloat162float(v);
}

// ordered-uint encoding for float atomicMax
static __device__ __forceinline__ unsigned int enc_f32(float f) {
    unsigned int u = __float_as_uint(f);
    return (u & 0x80000000u) ? ~u : (u | 0x80000000u);
}
static __device__ __forceinline__ float dec_f32(unsigned int u) {
    return __uint_as_float((u & 0x80000000u) ? (u & 0x7FFFFFFFu) : ~u);
}

typedef __bf16 bf16x8 __attribute__((ext_vector_type(8)));
typedef float f32x4 __attribute__((ext_vector_type(4)));

// async global->LDS, 16B per lane. LDS dest = wave-uniform base + lane*16.
static __device__ __forceinline__ void gload16(const void* g, void* l) {
    __builtin_amdgcn_global_load_lds(
        (const __attribute__((address_space(1))) void*)g,
        (__attribute__((address_space(3))) void*)l, 16, 0, 0);
}

// 32-bit LDS byte offset of a shared-memory pointer
static __device__ __forceinline__ unsigned ldsoff(const void* p) {
    return (unsigned)(size_t)(const __attribute__((address_space(3))) void*)p;
}

// opaque LDS read (invisible to the waitcnt pass; we do our own counted waits)
static __device__ __forceinline__ void ds_read_f4(unsigned addr, float4& out) {
    asm volatile("ds_read_b128 %0, %1" : "=v"(out) : "v"(addr) : "memory");
}

// opaque coalesced 16B global load with compile-time immediate offset
template<int OFF>
static __device__ __forceinline__ bf16x8 gld_b(const __bf16* p) {
    bf16x8 o;
    asm volatile("global_load_dwordx4 %0, %1, off offset:%2"
                 : "=v"(o) : "v"(p), "i"(OFF) : "memory");
    return o;
}

// ---------------------------------------------------------------- prep:
// W1 -> split-bf16 FRAGMENT-MAJOR layout (pure permutation of the 128x512
// transposed array; same 65536 elements, same workspace):
//   elem e = (((wc*16 + t)*4 + ct)*64 + lane)*8 + j
//   maps to col c = wc*64+ct*16+(lane&15), k = t*32+(lane>>4)*8+j.
// A wave's B-fragment load is then base+lane*16: perfectly coalesced 1KB.
// Also zeroes the int region (deg/start/cursor/gmax/zpad = 3N+96 ints).
__global__ void prep_kernel(const float* __restrict__ W1,
                            __bf16* __restrict__ w1t_hi,
                            __bf16* __restrict__ w1t_lo,
                            int* __restrict__ zp, int nz)
{
    int e = blockIdx.x * 256 + threadIdx.x;
    if (e < HC * KPAD) {
        int j = e & 7, lane = (e >> 3) & 63, ct = (e >> 9) & 3;
        int t = (e >> 11) & 15, wc = (e >> 15) & 1;
        int c = wc * 64 + ct * 16 + (lane & 15);
        int k = t * 32 + (lane >> 4) * 8 + j;
        float v = (k < F_IN) ? W1[k * HC + c] : 0.f;
        __bf16 h = (__bf16)v;
        w1t_hi[e] = h;
        w1t_lo[e] = (__bf16)(v - (float)h);
    }
    if (e < nz) zp[e] = 0;
}

// split 8 fp32 into bf16 hi + bf16 lo fragments
static __device__ __forceinline__ void split8(const float4 a, const float4 b,
                                              bf16x8& hi, bf16x8& lo) {
    float v[8] = {a.x, a.y, a.z, a.w, b.x, b.y, b.z, b.w};
#pragma unroll
    for (int j = 0; j < 8; j++) {
        __bf16 h = (__bf16)v[j];
        hi[j] = h;
        lo[j] = (__bf16)(v[j] - (float)h);
    }
}

// ---------------------------------------------------------------- GEMM1 v6 (MFMA, split-bf16):
// h1 = x @ W1 -> bf16 [N,128]. Block 64 rows x 128 cols, BK=32, 16 K-steps,
// 4 waves: wave (wr,wc) owns rows [wr*32,+32) x cols [wc*64,+64).
//  - B: fragment-major in global (L2-resident), loaded straight to registers
//    via coalesced inline-asm dwordx4, prefetched ONE step ahead. No LDS.
//  - A: global_load_lds into 4 x 8KB buffers, prefetched THREE steps ahead
//    (~1200cy >= 900cy HBM latency). Inline-asm ds_read fragments.
//  - All loop vmem is inline asm => vmcnt counting is exact. Per-iter issue
//    order [B(t+1):8, A(t+3):2]; steady wait vmcnt(12) completes exactly
//    {B(t), A(<=t+1)} (FIFO counter). Tail waits 10/8/0.
// MFMA order identical to v5: acc += Ah*Bh + Ah*Bl + Al*Bh (bit-identical).
__global__ __launch_bounds__(256, 2) void gemm1_v6(
    const float* __restrict__ x,
    const __bf16* __restrict__ w1hi, const __bf16* __restrict__ w1lo,
    const float* __restrict__ zpad,
    __hip_bfloat16* __restrict__ h1, int N)
{
    __shared__ float As[4][64 * 32];   // 32KB

    const int tid = threadIdx.x;
    const int lane = tid & 63, wave = tid >> 6;
    const int m = lane & 15, q = lane >> 4;
    const int wr = wave >> 1, wc = wave & 1;
    const int n0 = blockIdx.x * 64;
    const int woff = wave << 10;       // wave-uniform LDS byte offset

    // A stage: K-chunk t -> buffer buf (2 x global_load_lds per thread)
    auto stage = [&](int buf, int t) {
        const int k0 = t * 32;
#pragma unroll
        for (int j = 0; j < 2; ++j) {
            int idx = j * 256 + tid;
            int r = idx >> 3, ps = idx & 7;
            int ls = ps ^ (r & 7);
            int kk = k0 + ls * 4;
            int grow = n0 + r;
            const float* src = (kk < F_IN)
                ? (x + (size_t)(grow < N ? grow : 0) * F_IN + kk)
                : zpad;
            gload16(src, (char*)&As[buf][0] + j * 4096 + woff);
        }
    };

    // B per-lane fragment base (elems): wc-half + lane slot
    const __bf16* bh_base = w1hi + (size_t)wc * 32768 + (size_t)lane * 8;
    const __bf16* bl_base = w1lo + (size_t)wc * 32768 + (size_t)lane * 8;

    auto loadB = [&](bf16x8 (&bh)[4], bf16x8 (&bl)[4], int t) {
        const __bf16* ph = bh_base + (size_t)t * 2048;   // t*4096 bytes
        const __bf16* pl = bl_base + (size_t)t * 2048;
        bh[0] = gld_b<0>(ph);    bh[1] = gld_b<1024>(ph);
        bh[2] = gld_b<2048>(ph); bh[3] = gld_b<3072>(ph);
        bl[0] = gld_b<0>(pl);    bl[1] = gld_b<1024>(pl);
        bl[2] = gld_b<2048>(pl); bl[3] = gld_b<3072>(pl);
    };

    // LDS base offsets + per-lane A fragment offsets (row-swizzled 16B slots)
    unsigned abase[4];
#pragma unroll
    for (int i = 0; i < 4; ++i) abase[i] = ldsoff(&As[i][0]);
    unsigned aoffs[2][2];
#pragma unroll
    for (int rt = 0; rt < 2; ++rt) {
        int r = wr * 32 + rt * 16 + m, x7 = r & 7;
        aoffs[rt][0] = r * 128 + (((2 * q) ^ x7) << 4);
        aoffs[rt][1] = r * 128 + (((2 * q + 1) ^ x7) << 4);
    }

    f32x4 acc[2][4];
#pragma unroll
    for (int rt = 0; rt < 2; ++rt)
#pragma unroll
        for (int ct = 0; ct < 4; ++ct) acc[rt][ct] = (f32x4){0.f, 0.f, 0.f, 0.f};

    bf16x8 bhA[4], blA[4], bhB[4], blB[4];

    // prologue (issue order matters for FIFO vmcnt): A0, A1, B0, A2
    stage(0, 0);
    stage(1, 1);
    loadB(bhA, blA, 0);
    stage(2, 2);

    auto compute = [&](bf16x8 (&bh)[4], bf16x8 (&bl)[4],
                       bf16x8 (&ah)[2], bf16x8 (&al)[2]) {
        __builtin_amdgcn_s_setprio(1);
#pragma unroll
        for (int rt = 0; rt < 2; ++rt)
#pragma unroll
            for (int ct = 0; ct < 4; ++ct) {
                acc[rt][ct] = __builtin_amdgcn_mfma_f32_16x16x32_bf16(ah[rt], bh[ct], acc[rt][ct], 0, 0, 0);
                acc[rt][ct] = __builtin_amdgcn_mfma_f32_16x16x32_bf16(ah[rt], bl[ct], acc[rt][ct], 0, 0, 0);
                acc[rt][ct] = __builtin_amdgcn_mfma_f32_16x16x32_bf16(al[rt], bh[ct], acc[rt][ct], 0, 0, 0);
            }
        __builtin_amdgcn_s_setprio(0);
    };

#pragma unroll
    for (int t = 0; t < 16; ++t) {
        // top barrier: compute(t-1) ds_reads of buf (t-1)&3 done before
        // stage(t+3) DMA-writes the same buffer
        if (t > 0) __builtin_amdgcn_s_barrier();
        if (t + 1 < 16) {
            if ((t & 1) == 0) loadB(bhB, blB, t + 1);
            else              loadB(bhA, blA, t + 1);
        }
        if (t + 3 < 16) stage((t + 3) & 3, t + 3);

        // counted wait: completes exactly {B(t), A(<=t+1)} in FIFO order
        if (t <= 12)      asm volatile("s_waitcnt vmcnt(12)" ::: "memory");
        else if (t == 13) asm volatile("s_waitcnt vmcnt(10)" ::: "memory");
        else if (t == 14) asm volatile("s_waitcnt vmcnt(8)" ::: "memory");
        else              asm volatile("s_waitcnt vmcnt(0)" ::: "memory");
        __builtin_amdgcn_s_barrier();   // all waves' A(t) DMA visible

        const int cur = t & 3;
        float4 fa[2][2];
        ds_read_f4(abase[cur] + aoffs[0][0], fa[0][0]);
        ds_read_f4(abase[cur] + aoffs[0][1], fa[0][1]);
        ds_read_f4(abase[cur] + aoffs[1][0], fa[1][0]);
        ds_read_f4(abase[cur] + aoffs[1][1], fa[1][1]);
        asm volatile("s_waitcnt lgkmcnt(0)" ::: "memory");
        __builtin_amdgcn_sched_barrier(0);   // rule #18: pin uses after waits

        bf16x8 ah[2], al[2];
        split8(fa[0][0], fa[0][1], ah[0], al[0]);
        split8(fa[1][0], fa[1][1], ah[1], al[1]);

        if ((t & 1) == 0) compute(bhA, blA, ah, al);
        else              compute(bhB, blB, ah, al);
    }

    // store: C/D layout col=lane&15, row=(lane>>4)*4+reg
#pragma unroll
    for (int rt = 0; rt < 2; ++rt) {
        int rbase = n0 + wr * 32 + rt * 16 + q * 4;
#pragma unroll
        for (int ct = 0; ct < 4; ++ct) {
            int col = wc * 64 + ct * 16 + m;
#pragma unroll
            for (int r = 0; r < 4; ++r) {
                int row = rbase + r;
                if (row < N)
                    h1[(size_t)row * HC + col] = __float2bfloat16(acc[rt][ct][r]);
            }
        }
    }
}

// ---------------------------------------------------------------- per-node attention dots for layer 1
// d1[j*N*8 + n*8 + h] = sum_c h1[n,h,c] * a1[j,h,c]; fused per-head global max
// of d1m/d1t (replaces maxred_d1). h1 row read vectorized (2x bf16x8).
__global__ void dots1_kernel(const __hip_bfloat16* __restrict__ h1,
                             const float* __restrict__ a1,
                             float* __restrict__ d1,
                             unsigned int* __restrict__ gmax, int N)
{
    __shared__ unsigned int sm[16];
    if (threadIdx.x < 16) sm[threadIdx.x] = 0;
    __syncthreads();
    int id = blockIdx.x * blockDim.x + threadIdx.x;
    if (id < N * NHEAD) {
        int n = id >> 3, h = id & 7;
        const __hip_bfloat16* hp = h1 + (size_t)n * HC + h * CDIM;
        bf16x8 v0 = *(const bf16x8*)hp;
        bf16x8 v1 = *(const bf16x8*)(hp + 8);
        float s0 = 0.f, s1 = 0.f, s2 = 0.f;
#pragma unroll
        for (int c = 0; c < CDIM; c++) {
            float v = (c < 8) ? (float)v0[c & 7] : (float)v1[c & 7];
            s0 += v * a1[(0 * NHEAD + h) * CDIM + c];
            s1 += v * a1[(1 * NHEAD + h) * CDIM + c];
            s2 += v * a1[(2 * NHEAD + h) * CDIM + c];
        }
        d1[id] = s0;
        d1[N * NHEAD + id] = s1;
        d1[2 * N * NHEAD + id] = s2;
        atomicMax(&sm[h], enc_f32(s1));
        atomicMax(&sm[8 + h], enc_f32(s2));
    }
    __syncthreads();
    if (threadIdx.x < 16) atomicMax(&gmax[threadIdx.x], sm[threadIdx.x]);
}

// ---------------------------------------------------------------- CSR build
__global__ void hist_kernel(const int* __restrict__ pidx, int* __restrict__ deg, int P) {
    int p = blockIdx.x * blockDim.x + threadIdx.x;
    if (p < P) atomicAdd(deg + pidx[p], 1);
}

__global__ void scan1_kernel(const int* __restrict__ deg, int* __restrict__ start,
                             int* __restrict__ bsum, int N) {
    __shared__ int sh[256];
    int i = blockIdx.x * 256 + threadIdx.x;
    int v = (i < N) ? deg[i] : 0;
    sh[threadIdx.x] = v;
    __syncthreads();
#pragma unroll
    for (int off = 1; off < 256; off <<= 1) {
        int x = (threadIdx.x >= off) ? sh[threadIdx.x - off] : 0;
        __syncthreads();
        sh[threadIdx.x] += x;
        __syncthreads();
    }
    if (i < N) start[i] = sh[threadIdx.x] - v;   // exclusive
    if (threadIdx.x == 255) bsum[blockIdx.x] = sh[255];
}

__global__ void scan2_kernel(int* __restrict__ bsum, int nb) {
    __shared__ int sh[512];
    int v = (threadIdx.x < nb) ? bsum[threadIdx.x] : 0;
    sh[threadIdx.x] = v;
    __syncthreads();
#pragma unroll
    for (int off = 1; off < 512; off <<= 1) {
        int x = (threadIdx.x >= off) ? sh[threadIdx.x - off] : 0;
        __syncthreads();
        sh[threadIdx.x] += x;
        __syncthreads();
    }
    if (threadIdx.x < nb) bsum[threadIdx.x] = sh[threadIdx.x] - v;  // exclusive
}

__global__ void scan3_kernel(int* __restrict__ start, const int* __restrict__ bsum, int N) {
    int i = blockIdx.x * 256 + threadIdx.x;
    if (i < N) start[i] += bsum[blockIdx.x];
}

__global__ void scatter_kernel(const int* __restrict__ pidx,
                               const int* __restrict__ start,
                               int* __restrict__ cursor,
                               int* __restrict__ csr, int P) {
    int p = blockIdx.x * blockDim.x + threadIdx.x;
    if (p >= P) return;
    int hd = pidx[p];
    int pos = atomicAdd(cursor + hd, 1);
    csr[start[hd] + pos] = p;
}

// ---------------------------------------------------------------- layer1 attention, CSR, single pass.
// One wave per node. Softmax shift = upper bound leaky(dh + gm[h] + gt[h])
// (monotone leaky => bounds every path logit; softmax invariant to shift).
__global__ __launch_bounds__(256) void attn1_csr_kernel(
    const int* __restrict__ csr, const int* __restrict__ start,
    const int* __restrict__ deg, const int* __restrict__ pidx,
    const float* __restrict__ d1, const __hip_bfloat16* __restrict__ h1,
    const float* __restrict__ b1, const unsigned int* __restrict__ gmax,
    float* __restrict__ elu_out, int N, int P)
{
    int node = blockIdx.x * 4 + (threadIdx.x >> 6);
    if (node >= N) return;
    int lane = threadIdx.x & 63;
    int h = lane >> 3;
    int s0 = start[node], dg = deg[node];
    const float* d1m = d1 + (size_t)N * NHEAD;
    const float* d1t = d1 + (size_t)2 * N * NHEAD;
    const float dh = d1[node * NHEAD + h];
    float zub = dh + dec_f32(gmax[h]) + dec_f32(gmax[8 + h]);
    const float mxub = zub > 0.f ? zub : 0.2f * zub;

    float acc0 = 0.f, acc1 = 0.f, den = 0.f;
    for (int k0 = 0; k0 < dg; k0 += 8) {
        int kk = k0 + (lane & 7);
        bool valid = kk < dg;
        int p = csr[s0 + (valid ? kk : dg - 1)];
        int mid = pidx[P + p], tl = pidx[2 * P + p];
        float z = dh + d1m[mid * NHEAD + h] + d1t[tl * NHEAD + h];
        float e = z > 0.f ? z : 0.2f * z;
        float ex = valid ? __expf(e - mxub) : 0.f;
        den += ex;
        int kmax = dg - k0; if (kmax > 8) kmax = 8;
        for (int dk = 0; dk < kmax; dk++) {
            int tl_b = __shfl(tl, dk, 8);
            float ex_b = __shfl(ex, dk, 8);
            __hip_bfloat162 v = *(const __hip_bfloat162*)(h1 + (size_t)tl_b * HC + 2 * lane);
            acc0 += ex_b * bf(v.x);
            acc1 += ex_b * bf(v.y);
        }
    }
#pragma unroll
    for (int w = 1; w < 8; w <<= 1) den += __shfl_xor(den, w, 8);

    float inv = 1.f / (den + 1e-16f);
    int j0 = 2 * lane;
    float v0 = acc0 * inv + b1[j0];
    float v1 = acc1 * inv + b1[j0 + 1];
    v0 = v0 > 0.f ? v0 : __expf(v0) - 1.f;
    v1 = v1 > 0.f ? v1 : __expf(v1) - 1.f;
    *(float2*)(elu_out + (size_t)node * HC + j0) = make_float2(v0, v1);
}

// ---------------------------------------------------------------- layer2 GEMM + dots: h2 = elu @ W2 ; d2[j,n] = h2[n,:]·a2[j]
// fused global max of d2m/d2t (replaces maxred_d2)
__global__ __launch_bounds__(256) void layer2_kernel(
    const float* __restrict__ elu, const float* __restrict__ W2,
    const float* __restrict__ a2,
    float* __restrict__ h2, float* __restrict__ d2,
    unsigned int* __restrict__ gmax2, int N)
{
    __shared__ float rows[16][HC + 1];
    __shared__ float h2s[16][NCLS + 1];
    __shared__ unsigned int smax[2];
    const int n0 = blockIdx.x * 16;
    const int tid = threadIdx.x;
    if (tid < 2) smax[tid] = 0;
    for (int idx = tid; idx < 16 * HC; idx += 256) {
        int r = idx >> 7, c = idx & 127;
        rows[r][c] = (n0 + r < N) ? elu[(size_t)(n0 + r) * HC + c] : 0.f;
    }
    __syncthreads();
    int ln = tid >> 4, c = tid & 15;
    float acc = 0.f;
#pragma unroll 8
    for (int j = 0; j < HC; j++) acc += rows[ln][j] * W2[j * NCLS + c];
    h2s[ln][c] = acc;
    if (n0 + ln < N) h2[(size_t)(n0 + ln) * NCLS + c] = acc;
    __syncthreads();
    if (tid < 48) {
        int l = tid / 3, j = tid - l * 3;
        if (n0 + l < N) {
            float s = 0.f;
#pragma unroll
            for (int cc = 0; cc < NCLS; cc++) s += h2s[l][cc] * a2[j * NCLS + cc];
            d2[j * N + n0 + l] = s;
            if (j) atomicMax(&smax[j - 1], enc_f32(s));
        }
    }
    __syncthreads();
    if (tid < 2) atomicMax(&gmax2[tid], smax[tid]);
}

// ---------------------------------------------------------------- layer2 attention CSR, single pass + log_softmax -> out (fp32)
__global__ __launch_bounds__(256) void attn2_csr_kernel(
    const int* __restrict__ csr, const int* __restrict__ start,
    const int* __restrict__ deg, const int* __restrict__ pidx,
    const float* __restrict__ d2, const float* __restrict__ h2,
    const float* __restrict__ b2, const unsigned int* __restrict__ gmax2,
    float* __restrict__ out, int N, int P)
{
    int node = blockIdx.x * 16 + (threadIdx.x >> 4);
    if (node >= N) return;
    int c = threadIdx.x & 15;
    int s0 = start[node], dg = deg[node];
    const float dh = d2[node];
    const float* d2m = d2 + N;
    const float* d2t = d2 + 2 * N;
    float zub = dh + dec_f32(gmax2[0]) + dec_f32(gmax2[1]);
    const float mxub = zub > 0.f ? zub : 0.2f * zub;

    float acc = 0.f, den = 0.f;
    for (int k0 = 0; k0 < dg; k0 += 16) {
        int kk = k0 + c;
        bool valid = kk < dg;
        int p = csr[s0 + (valid ? kk : dg - 1)];
        int mid = pidx[P + p], tl = pidx[2 * P + p];
        float z = dh + d2m[mid] + d2t[tl];
        float e = z > 0.f ? z : 0.2f * z;
        float ex = valid ? __expf(e - mxub) : 0.f;
        den += ex;
        int kmax = dg - k0; if (kmax > 16) kmax = 16;
        for (int dk = 0; dk < kmax; dk++) {
            int tl_b = __shfl(tl, dk, 16);
            float ex_b = __shfl(ex, dk, 16);
            acc += ex_b * h2[(size_t)tl_b * NCLS + c];
        }
    }
#pragma unroll
    for (int w = 1; w < 16; w <<= 1) den += __shfl_xor(den, w, 16);

    float o = acc / (den + 1e-16f) + b2[c];
    // log_softmax across the 16 lanes of this node
    float m2 = o;
#pragma unroll
    for (int w = 1; w < 16; w <<= 1) m2 = fmaxf(m2, __shfl_xor(m2, w, 16));
    float ex = __expf(o - m2), sm = ex;
#pragma unroll
    for (int w = 1; w < 16; w <<= 1) sm += __shfl_xor(sm, w, 16);
    float r = o - m2 - __logf(sm);
    out[(size_t)node * NCLS + c] = r;
}

// ================================================================ launch
extern "C" void kernel_launch(void* const* d_in, const int* in_sizes, int n_in,
                              void* d_out, int out_size, void* d_ws, size_t ws_size,
                              hipStream_t stream)
{
    const float* x  = (const float*)d_in[0];
    const int*   pi = (const int*)d_in[1];
    const float* W1 = (const float*)d_in[2];
    const float* a1 = (const float*)d_in[3];
    const float* b1 = (const float*)d_in[4];
    const float* W2 = (const float*)d_in[5];
    const float* a2 = (const float*)d_in[6];
    const float* b2 = (const float*)d_in[7];

    const int N = in_sizes[0] / F_IN;   // 100000
    const int P = in_sizes[1] / 3;      // 1000000

    float* ws = (float*)d_ws;
    // workspace (float units): peak ~238N + P + 68k floats (~99.5 MB)
    size_t off_h1     = 0;                          // 64N  (bf16 x 128N)
    size_t off_d1     = (size_t)64 * N;             // 24N
    size_t off_elu    = (size_t)88 * N;             // 128N
    size_t off_h2     = (size_t)216 * N;            // 16N
    size_t off_d2     = (size_t)232 * N;            // 3N
    size_t off_deg    = (size_t)235 * N;            // N (int)
    size_t off_start  = (size_t)236 * N;            // N (int)
    size_t off_cursor = (size_t)237 * N;            // N (int)
    size_t off_gmax   = (size_t)238 * N;            // 32 (uint: 16 for d1, 2 for d2)
    size_t off_zpad   = (size_t)238 * N + 32;       // 64 (float, zeroed; 16B-aligned pad for gemm1 k>=500)
    size_t off_bsum   = (size_t)238 * N + 96;       // 1024 (int)
    size_t off_csr    = (size_t)238 * N + 96 + 1024; // P (int)
    size_t off_w1th   = off_csr + P;                // 32768 (bf16 x 65536)
    size_t off_w1tl   = off_w1th + 32768;           // 32768

    __hip_bfloat16* h1 = (__hip_bfloat16*)(ws + off_h1);
    float* d1   = ws + off_d1;
    float* elu  = ws + off_elu;
    float* h2   = ws + off_h2;
    float* d2   = ws + off_d2;
    int* deg    = (int*)(ws + off_deg);
    int* start  = (int*)(ws + off_start);
    int* cursor = (int*)(ws + off_cursor);
    unsigned int* gmax  = (unsigned int*)(ws + off_gmax);       // 16
    unsigned int* gmax2 = (unsigned int*)(ws + off_gmax) + 16;  // 2
    float* zpad = ws + off_zpad;
    int* bsum   = (int*)(ws + off_bsum);
    int* csr    = (int*)(ws + off_csr);
    __bf16* w1t_hi = (__bf16*)(ws + off_w1th);
    __bf16* w1t_lo = (__bf16*)(ws + off_w1tl);

    const int BLK = 256;
    const int nb = (N + 255) / 256;   // scan blocks (<= 512)
    const int nz = 3 * N + 96;        // deg..zpad zero region
    const int nprep = (HC * KPAD > nz ? HC * KPAD : nz);

    prep_kernel<<<(nprep + 255) / 256, 256, 0, stream>>>(W1, w1t_hi, w1t_lo, deg, nz);
    gemm1_v6<<<(N + 63) / 64, 256, 0, stream>>>(x, w1t_hi, w1t_lo, zpad, h1, N);
    dots1_kernel<<<(N * NHEAD + BLK - 1) / BLK, BLK, 0, stream>>>(h1, a1, d1, gmax, N);
    // CSR build
    hist_kernel<<<(P + BLK - 1) / BLK, BLK, 0, stream>>>(pi, deg, P);
    scan1_kernel<<<nb, 256, 0, stream>>>(deg, start, bsum, N);
    scan2_kernel<<<1, 512, 0, stream>>>(bsum, nb);
    scan3_kernel<<<nb, 256, 0, stream>>>(start, bsum, N);
    scatter_kernel<<<(P + BLK - 1) / BLK, BLK, 0, stream>>>(pi, start, cursor, csr, P);
    // layer 1 attention (single-pass, fused softmax/aggregate/bias/elu)
    attn1_csr_kernel<<<(N + 3) / 4, 256, 0, stream>>>(csr, start, deg, pi, d1, h1, b1, gmax, elu, N, P);
    // layer 2
    layer2_kernel<<<(N + 15) / 16, 256, 0, stream>>>(elu, W2, a2, h2, d2, gmax2, N);
    attn2_csr_kernel<<<(N + 15) / 16, 256, 0, stream>>>(csr, start, deg, pi, d2, h2, b2, gmax2,
                                                        (float*)d_out, N, P);
}

// Round 8
// 699.757 us; speedup vs baseline: 1.1038x; 1.0360x over previous
//
#include <hip/hip_runtime.h>
#include <hip/hip_bf16.h>

// Problem constants (shapes fixed by setup_inputs). All float I/O is fp32
// (established round 4: hardcoded-bf16 reads NaN'd twice; flag-version passed).
#define F_IN  500
#define HC    128   // H*C
#define NHEAD 8
#define CDIM  16
#define NCLS  16
#define KPAD  512   // F_IN padded to multiple of 32 for MFMA K-loop

static __device__ __forceinline__ float bf(const __hip_bfloat16 v) {
    return __bfloat162float(v);
}

// ordered-uint encoding for float atomicMax
static __device__ __forceinline__ unsigned int enc_f32(float f) {
    unsigned int u = __float_as_uint(f);
    return (u & 0x80000000u) ? ~u : (u | 0x80000000u);
}
static __device__ __forceinline__ float dec_f32(unsigned int u) {
    return __uint_as_float((u & 0x80000000u) ? (u & 0x7FFFFFFFu) : ~u);
}

typedef __bf16 bf16x8 __attribute__((ext_vector_type(8)));
typedef float f32x4 __attribute__((ext_vector_type(4)));

// async global->LDS, 16B per lane. LDS dest = wave-uniform base + lane*16.
static __device__ __forceinline__ void gload16(const void* g, void* l) {
    __builtin_amdgcn_global_load_lds(
        (const __attribute__((address_space(1))) void*)g,
        (__attribute__((address_space(3))) void*)l, 16, 0, 0);
}

// 32-bit LDS byte offset of a shared-memory pointer
static __device__ __forceinline__ unsigned ldsoff(const void* p) {
    return (unsigned)(size_t)(const __attribute__((address_space(3))) void*)p;
}

// opaque LDS read (invisible to the waitcnt pass; we do our own counted waits)
static __device__ __forceinline__ void ds_read_f4(unsigned addr, float4& out) {
    asm volatile("ds_read_b128 %0, %1" : "=v"(out) : "v"(addr) : "memory");
}

// opaque coalesced 16B global load with compile-time immediate offset
template<int OFF>
static __device__ __forceinline__ bf16x8 gld_b(const __bf16* p) {
    bf16x8 o;
    asm volatile("global_load_dwordx4 %0, %1, off offset:%2"
                 : "=v"(o) : "v"(p), "i"(OFF) : "memory");
    return o;
}

// ---------------------------------------------------------------- prep:
// W1 -> split-bf16 FRAGMENT-MAJOR layout (pure permutation of the 128x512
// transposed array; same 65536 elements, same workspace):
//   elem e = (((wc*16 + t)*4 + ct)*64 + lane)*8 + j
//   maps to col c = wc*64+ct*16+(lane&15), k = t*32+(lane>>4)*8+j.
// A wave's B-fragment load is then base+lane*16: perfectly coalesced 1KB.
// Also zeroes the int region (deg/start/cursor/gmax/zpad = 3N+96 ints).
__global__ void prep_kernel(const float* __restrict__ W1,
                            __bf16* __restrict__ w1t_hi,
                            __bf16* __restrict__ w1t_lo,
                            int* __restrict__ zp, int nz)
{
    int e = blockIdx.x * 256 + threadIdx.x;
    if (e < HC * KPAD) {
        int j = e & 7, lane = (e >> 3) & 63, ct = (e >> 9) & 3;
        int t = (e >> 11) & 15, wc = (e >> 15) & 1;
        int c = wc * 64 + ct * 16 + (lane & 15);
        int k = t * 32 + (lane >> 4) * 8 + j;
        float v = (k < F_IN) ? W1[k * HC + c] : 0.f;
        __bf16 h = (__bf16)v;
        w1t_hi[e] = h;
        w1t_lo[e] = (__bf16)(v - (float)h);
    }
    if (e < nz) zp[e] = 0;
}

// split 8 fp32 into bf16 hi + bf16 lo fragments
static __device__ __forceinline__ void split8(const float4 a, const float4 b,
                                              bf16x8& hi, bf16x8& lo) {
    float v[8] = {a.x, a.y, a.z, a.w, b.x, b.y, b.z, b.w};
#pragma unroll
    for (int j = 0; j < 8; j++) {
        __bf16 h = (__bf16)v[j];
        hi[j] = h;
        lo[j] = (__bf16)(v[j] - (float)h);
    }
}

// ---------------------------------------------------------------- GEMM1 v6 (MFMA, split-bf16):
// h1 = x @ W1 -> bf16 [N,128]. Block 64 rows x 128 cols, BK=32, 16 K-steps,
// 4 waves: wave (wr,wc) owns rows [wr*32,+32) x cols [wc*64,+64).
//  - B: fragment-major in global (L2-resident), loaded straight to registers
//    via coalesced inline-asm dwordx4, prefetched ONE step ahead. No LDS.
//  - A: global_load_lds into 4 x 8KB buffers, prefetched THREE steps ahead
//    (~1200cy >= 900cy HBM latency). Inline-asm ds_read fragments.
//  - All loop vmem is inline asm => vmcnt counting is exact. Per-iter issue
//    order [B(t+1):8, A(t+3):2]; steady wait vmcnt(12) completes exactly
//    {B(t), A(<=t+1)} (FIFO counter). Tail waits 10/8/0.
//  - launch_bounds(256,2): PROVEN config (round 5). (256,4) caps VGPR at 128
//    -> spills interleave scratch vmem with the manually-counted asm loads
//    (compiler treats asm load results as instantly ready) -> R6/R7 aborts.
// MFMA order identical to v5: acc += Ah*Bh + Ah*Bl + Al*Bh (bit-identical).
__global__ __launch_bounds__(256, 2) void gemm1_v6(
    const float* __restrict__ x,
    const __bf16* __restrict__ w1hi, const __bf16* __restrict__ w1lo,
    const float* __restrict__ zpad,
    __hip_bfloat16* __restrict__ h1, int N)
{
    __shared__ float As[4][64 * 32];   // 32KB

    const int tid = threadIdx.x;
    const int lane = tid & 63, wave = tid >> 6;
    const int m = lane & 15, q = lane >> 4;
    const int wr = wave >> 1, wc = wave & 1;
    const int n0 = blockIdx.x * 64;
    const int woff = wave << 10;       // wave-uniform LDS byte offset

    // A stage: K-chunk t -> buffer buf (2 x global_load_lds per thread)
    auto stage = [&](int buf, int t) {
        const int k0 = t * 32;
#pragma unroll
        for (int j = 0; j < 2; ++j) {
            int idx = j * 256 + tid;
            int r = idx >> 3, ps = idx & 7;
            int ls = ps ^ (r & 7);
            int kk = k0 + ls * 4;
            int grow = n0 + r;
            const float* src = (kk < F_IN)
                ? (x + (size_t)(grow < N ? grow : 0) * F_IN + kk)
                : zpad;
            gload16(src, (char*)&As[buf][0] + j * 4096 + woff);
        }
    };

    // B per-lane fragment base (elems): wc-half + lane slot
    const __bf16* bh_base = w1hi + (size_t)wc * 32768 + (size_t)lane * 8;
    const __bf16* bl_base = w1lo + (size_t)wc * 32768 + (size_t)lane * 8;

    auto loadB = [&](bf16x8 (&bh)[4], bf16x8 (&bl)[4], int t) {
        const __bf16* ph = bh_base + (size_t)t * 2048;   // t*4096 bytes
        const __bf16* pl = bl_base + (size_t)t * 2048;
        bh[0] = gld_b<0>(ph);    bh[1] = gld_b<1024>(ph);
        bh[2] = gld_b<2048>(ph); bh[3] = gld_b<3072>(ph);
        bl[0] = gld_b<0>(pl);    bl[1] = gld_b<1024>(pl);
        bl[2] = gld_b<2048>(pl); bl[3] = gld_b<3072>(pl);
    };

    // LDS base offsets + per-lane A fragment offsets (row-swizzled 16B slots)
    unsigned abase[4];
#pragma unroll
    for (int i = 0; i < 4; ++i) abase[i] = ldsoff(&As[i][0]);
    unsigned aoffs[2][2];
#pragma unroll
    for (int rt = 0; rt < 2; ++rt) {
        int r = wr * 32 + rt * 16 + m, x7 = r & 7;
        aoffs[rt][0] = r * 128 + (((2 * q) ^ x7) << 4);
        aoffs[rt][1] = r * 128 + (((2 * q + 1) ^ x7) << 4);
    }

    f32x4 acc[2][4];
#pragma unroll
    for (int rt = 0; rt < 2; ++rt)
#pragma unroll
        for (int ct = 0; ct < 4; ++ct) acc[rt][ct] = (f32x4){0.f, 0.f, 0.f, 0.f};

    bf16x8 bhA[4], blA[4], bhB[4], blB[4];

    // prologue (issue order matters for FIFO vmcnt): A0, A1, B0, A2
    stage(0, 0);
    stage(1, 1);
    loadB(bhA, blA, 0);
    stage(2, 2);

    auto compute = [&](bf16x8 (&bh)[4], bf16x8 (&bl)[4],
                       bf16x8 (&ah)[2], bf16x8 (&al)[2]) {
        __builtin_amdgcn_s_setprio(1);
#pragma unroll
        for (int rt = 0; rt < 2; ++rt)
#pragma unroll
            for (int ct = 0; ct < 4; ++ct) {
                acc[rt][ct] = __builtin_amdgcn_mfma_f32_16x16x32_bf16(ah[rt], bh[ct], acc[rt][ct], 0, 0, 0);
                acc[rt][ct] = __builtin_amdgcn_mfma_f32_16x16x32_bf16(ah[rt], bl[ct], acc[rt][ct], 0, 0, 0);
                acc[rt][ct] = __builtin_amdgcn_mfma_f32_16x16x32_bf16(al[rt], bh[ct], acc[rt][ct], 0, 0, 0);
            }
        __builtin_amdgcn_s_setprio(0);
    };

#pragma unroll
    for (int t = 0; t < 16; ++t) {
        // top barrier: compute(t-1) ds_reads of buf (t-1)&3 done before
        // stage(t+3) DMA-writes the same buffer
        if (t > 0) __builtin_amdgcn_s_barrier();
        if (t + 1 < 16) {
            if ((t & 1) == 0) loadB(bhB, blB, t + 1);
            else              loadB(bhA, blA, t + 1);
        }
        if (t + 3 < 16) stage((t + 3) & 3, t + 3);

        // counted wait: completes exactly {B(t), A(<=t+1)} in FIFO order
        if (t <= 12)      asm volatile("s_waitcnt vmcnt(12)" ::: "memory");
        else if (t == 13) asm volatile("s_waitcnt vmcnt(10)" ::: "memory");
        else if (t == 14) asm volatile("s_waitcnt vmcnt(8)" ::: "memory");
        else              asm volatile("s_waitcnt vmcnt(0)" ::: "memory");
        __builtin_amdgcn_s_barrier();   // all waves' A(t) DMA visible

        const int cur = t & 3;
        float4 fa[2][2];
        ds_read_f4(abase[cur] + aoffs[0][0], fa[0][0]);
        ds_read_f4(abase[cur] + aoffs[0][1], fa[0][1]);
        ds_read_f4(abase[cur] + aoffs[1][0], fa[1][0]);
        ds_read_f4(abase[cur] + aoffs[1][1], fa[1][1]);
        asm volatile("s_waitcnt lgkmcnt(0)" ::: "memory");
        __builtin_amdgcn_sched_barrier(0);   // rule #18: pin uses after waits

        bf16x8 ah[2], al[2];
        split8(fa[0][0], fa[0][1], ah[0], al[0]);
        split8(fa[1][0], fa[1][1], ah[1], al[1]);

        if ((t & 1) == 0) compute(bhA, blA, ah, al);
        else              compute(bhB, blB, ah, al);
    }

    // store: C/D layout col=lane&15, row=(lane>>4)*4+reg
#pragma unroll
    for (int rt = 0; rt < 2; ++rt) {
        int rbase = n0 + wr * 32 + rt * 16 + q * 4;
#pragma unroll
        for (int ct = 0; ct < 4; ++ct) {
            int col = wc * 64 + ct * 16 + m;
#pragma unroll
            for (int r = 0; r < 4; ++r) {
                int row = rbase + r;
                if (row < N)
                    h1[(size_t)row * HC + col] = __float2bfloat16(acc[rt][ct][r]);
            }
        }
    }
}

// ---------------------------------------------------------------- per-node attention dots for layer 1
// d1[j*N*8 + n*8 + h] = sum_c h1[n,h,c] * a1[j,h,c]; fused per-head global max
// of d1m/d1t (replaces maxred_d1). h1 row read vectorized (2x bf16x8).
__global__ void dots1_kernel(const __hip_bfloat16* __restrict__ h1,
                             const float* __restrict__ a1,
                             float* __restrict__ d1,
                             unsigned int* __restrict__ gmax, int N)
{
    __shared__ unsigned int sm[16];
    if (threadIdx.x < 16) sm[threadIdx.x] = 0;
    __syncthreads();
    int id = blockIdx.x * blockDim.x + threadIdx.x;
    if (id < N * NHEAD) {
        int n = id >> 3, h = id & 7;
        const __hip_bfloat16* hp = h1 + (size_t)n * HC + h * CDIM;
        bf16x8 v0 = *(const bf16x8*)hp;
        bf16x8 v1 = *(const bf16x8*)(hp + 8);
        float s0 = 0.f, s1 = 0.f, s2 = 0.f;
#pragma unroll
        for (int c = 0; c < CDIM; c++) {
            float v = (c < 8) ? (float)v0[c & 7] : (float)v1[c & 7];
            s0 += v * a1[(0 * NHEAD + h) * CDIM + c];
            s1 += v * a1[(1 * NHEAD + h) * CDIM + c];
            s2 += v * a1[(2 * NHEAD + h) * CDIM + c];
        }
        d1[id] = s0;
        d1[N * NHEAD + id] = s1;
        d1[2 * N * NHEAD + id] = s2;
        atomicMax(&sm[h], enc_f32(s1));
        atomicMax(&sm[8 + h], enc_f32(s2));
    }
    __syncthreads();
    if (threadIdx.x < 16) atomicMax(&gmax[threadIdx.x], sm[threadIdx.x]);
}

// ---------------------------------------------------------------- CSR build
__global__ void hist_kernel(const int* __restrict__ pidx, int* __restrict__ deg, int P) {
    int p = blockIdx.x * blockDim.x + threadIdx.x;
    if (p < P) atomicAdd(deg + pidx[p], 1);
}

__global__ void scan1_kernel(const int* __restrict__ deg, int* __restrict__ start,
                             int* __restrict__ bsum, int N) {
    __shared__ int sh[256];
    int i = blockIdx.x * 256 + threadIdx.x;
    int v = (i < N) ? deg[i] : 0;
    sh[threadIdx.x] = v;
    __syncthreads();
#pragma unroll
    for (int off = 1; off < 256; off <<= 1) {
        int x = (threadIdx.x >= off) ? sh[threadIdx.x - off] : 0;
        __syncthreads();
        sh[threadIdx.x] += x;
        __syncthreads();
    }
    if (i < N) start[i] = sh[threadIdx.x] - v;   // exclusive
    if (threadIdx.x == 255) bsum[blockIdx.x] = sh[255];
}

__global__ void scan2_kernel(int* __restrict__ bsum, int nb) {
    __shared__ int sh[512];
    int v = (threadIdx.x < nb) ? bsum[threadIdx.x] : 0;
    sh[threadIdx.x] = v;
    __syncthreads();
#pragma unroll
    for (int off = 1; off < 512; off <<= 1) {
        int x = (threadIdx.x >= off) ? sh[threadIdx.x - off] : 0;
        __syncthreads();
        sh[threadIdx.x] += x;
        __syncthreads();
    }
    if (threadIdx.x < nb) bsum[threadIdx.x] = sh[threadIdx.x] - v;  // exclusive
}

__global__ void scan3_kernel(int* __restrict__ start, const int* __restrict__ bsum, int N) {
    int i = blockIdx.x * 256 + threadIdx.x;
    if (i < N) start[i] += bsum[blockIdx.x];
}

__global__ void scatter_kernel(const int* __restrict__ pidx,
                               const int* __restrict__ start,
                               int* __restrict__ cursor,
                               int* __restrict__ csr, int P) {
    int p = blockIdx.x * blockDim.x + threadIdx.x;
    if (p >= P) return;
    int hd = pidx[p];
    int pos = atomicAdd(cursor + hd, 1);
    csr[start[hd] + pos] = p;
}

// ---------------------------------------------------------------- layer1 attention, CSR, single pass.
// One wave per node. Softmax shift = upper bound leaky(dh + gm[h] + gt[h]).
// ONLY change vs the round-5-proven kernel: the inner gather is hoisted --
// per 8-path group, all 8 h1-row gathers issue into registers (independent
// loads in flight) before the FMA chain. Padded slots clamp to path dg-1,
// whose row equals the last valid slot's row (same cache line, ~no extra
// traffic), and contribute exact +0.0f in the same dk positions.
__global__ __launch_bounds__(256) void attn1_csr_kernel(
    const int* __restrict__ csr, const int* __restrict__ start,
    const int* __restrict__ deg, const int* __restrict__ pidx,
    const float* __restrict__ d1, const __hip_bfloat16* __restrict__ h1,
    const float* __restrict__ b1, const unsigned int* __restrict__ gmax,
    float* __restrict__ elu_out, int N, int P)
{
    int node = blockIdx.x * 4 + (threadIdx.x >> 6);
    if (node >= N) return;
    int lane = threadIdx.x & 63;
    int h = lane >> 3;
    int s0 = start[node], dg = deg[node];
    const float* d1m = d1 + (size_t)N * NHEAD;
    const float* d1t = d1 + (size_t)2 * N * NHEAD;
    const float dh = d1[node * NHEAD + h];
    float zub = dh + dec_f32(gmax[h]) + dec_f32(gmax[8 + h]);
    const float mxub = zub > 0.f ? zub : 0.2f * zub;

    float acc0 = 0.f, acc1 = 0.f, den = 0.f;
    for (int k0 = 0; k0 < dg; k0 += 8) {
        int kk = k0 + (lane & 7);
        bool valid = kk < dg;
        int p = csr[s0 + (valid ? kk : dg - 1)];
        int mid = pidx[P + p], tl = pidx[2 * P + p];
        float z = dh + d1m[mid * NHEAD + h] + d1t[tl * NHEAD + h];
        float e = z > 0.f ? z : 0.2f * z;
        float ex = valid ? __expf(e - mxub) : 0.f;
        den += ex;
        // hoisted gather: 8 independent row loads in flight
        __hip_bfloat162 v[8];
        float exs[8];
#pragma unroll
        for (int dk = 0; dk < 8; dk++) {
            int tl_b = __shfl(tl, dk, 8);
            exs[dk] = __shfl(ex, dk, 8);
            v[dk] = *(const __hip_bfloat162*)(h1 + (size_t)tl_b * HC + 2 * lane);
        }
#pragma unroll
        for (int dk = 0; dk < 8; dk++) {
            acc0 += exs[dk] * bf(v[dk].x);
            acc1 += exs[dk] * bf(v[dk].y);
        }
    }
#pragma unroll
    for (int w = 1; w < 8; w <<= 1) den += __shfl_xor(den, w, 8);

    float inv = 1.f / (den + 1e-16f);
    int j0 = 2 * lane;
    float v0 = acc0 * inv + b1[j0];
    float v1 = acc1 * inv + b1[j0 + 1];
    v0 = v0 > 0.f ? v0 : __expf(v0) - 1.f;
    v1 = v1 > 0.f ? v1 : __expf(v1) - 1.f;
    *(float2*)(elu_out + (size_t)node * HC + j0) = make_float2(v0, v1);
}

// ---------------------------------------------------------------- layer2 GEMM + dots: h2 = elu @ W2 ; d2[j,n] = h2[n,:]·a2[j]
// fused global max of d2m/d2t (replaces maxred_d2)
__global__ __launch_bounds__(256) void layer2_kernel(
    const float* __restrict__ elu, const float* __restrict__ W2,
    const float* __restrict__ a2,
    float* __restrict__ h2, float* __restrict__ d2,
    unsigned int* __restrict__ gmax2, int N)
{
    __shared__ float rows[16][HC + 1];
    __shared__ float h2s[16][NCLS + 1];
    __shared__ unsigned int smax[2];
    const int n0 = blockIdx.x * 16;
    const int tid = threadIdx.x;
    if (tid < 2) smax[tid] = 0;
    for (int idx = tid; idx < 16 * HC; idx += 256) {
        int r = idx >> 7, c = idx & 127;
        rows[r][c] = (n0 + r < N) ? elu[(size_t)(n0 + r) * HC + c] : 0.f;
    }
    __syncthreads();
    int ln = tid >> 4, c = tid & 15;
    float acc = 0.f;
#pragma unroll 8
    for (int j = 0; j < HC; j++) acc += rows[ln][j] * W2[j * NCLS + c];
    h2s[ln][c] = acc;
    if (n0 + ln < N) h2[(size_t)(n0 + ln) * NCLS + c] = acc;
    __syncthreads();
    if (tid < 48) {
        int l = tid / 3, j = tid - l * 3;
        if (n0 + l < N) {
            float s = 0.f;
#pragma unroll
            for (int cc = 0; cc < NCLS; cc++) s += h2s[l][cc] * a2[j * NCLS + cc];
            d2[j * N + n0 + l] = s;
            if (j) atomicMax(&smax[j - 1], enc_f32(s));
        }
    }
    __syncthreads();
    if (tid < 2) atomicMax(&gmax2[tid], smax[tid]);
}

// ---------------------------------------------------------------- layer2 attention CSR, single pass + log_softmax -> out (fp32)
// Same hoisted-gather restructure (16-deep, fp32 rows).
__global__ __launch_bounds__(256) void attn2_csr_kernel(
    const int* __restrict__ csr, const int* __restrict__ start,
    const int* __restrict__ deg, const int* __restrict__ pidx,
    const float* __restrict__ d2, const float* __restrict__ h2,
    const float* __restrict__ b2, const unsigned int* __restrict__ gmax2,
    float* __restrict__ out, int N, int P)
{
    int node = blockIdx.x * 16 + (threadIdx.x >> 4);
    if (node >= N) return;
    int c = threadIdx.x & 15;
    int s0 = start[node], dg = deg[node];
    const float dh = d2[node];
    const float* d2m = d2 + N;
    const float* d2t = d2 + 2 * N;
    float zub = dh + dec_f32(gmax2[0]) + dec_f32(gmax2[1]);
    const float mxub = zub > 0.f ? zub : 0.2f * zub;

    float acc = 0.f, den = 0.f;
    for (int k0 = 0; k0 < dg; k0 += 16) {
        int kk = k0 + c;
        bool valid = kk < dg;
        int p = csr[s0 + (valid ? kk : dg - 1)];
        int mid = pidx[P + p], tl = pidx[2 * P + p];
        float z = dh + d2m[mid] + d2t[tl];
        float e = z > 0.f ? z : 0.2f * z;
        float ex = valid ? __expf(e - mxub) : 0.f;
        den += ex;
        // hoisted gather: 16 independent loads in flight
        float vv[16], exs[16];
#pragma unroll
        for (int dk = 0; dk < 16; dk++) {
            int tl_b = __shfl(tl, dk, 16);
            exs[dk] = __shfl(ex, dk, 16);
            vv[dk] = h2[(size_t)tl_b * NCLS + c];
        }
#pragma unroll
        for (int dk = 0; dk < 16; dk++) acc += exs[dk] * vv[dk];
    }
#pragma unroll
    for (int w = 1; w < 16; w <<= 1) den += __shfl_xor(den, w, 16);

    float o = acc / (den + 1e-16f) + b2[c];
    // log_softmax across the 16 lanes of this node
    float m2 = o;
#pragma unroll
    for (int w = 1; w < 16; w <<= 1) m2 = fmaxf(m2, __shfl_xor(m2, w, 16));
    float ex = __expf(o - m2), sm = ex;
#pragma unroll
    for (int w = 1; w < 16; w <<= 1) sm += __shfl_xor(sm, w, 16);
    float r = o - m2 - __logf(sm);
    out[(size_t)node * NCLS + c] = r;
}

// ================================================================ launch
extern "C" void kernel_launch(void* const* d_in, const int* in_sizes, int n_in,
                              void* d_out, int out_size, void* d_ws, size_t ws_size,
                              hipStream_t stream)
{
    const float* x  = (const float*)d_in[0];
    const int*   pi = (const int*)d_in[1];
    const float* W1 = (const float*)d_in[2];
    const float* a1 = (const float*)d_in[3];
    const float* b1 = (const float*)d_in[4];
    const float* W2 = (const float*)d_in[5];
    const float* a2 = (const float*)d_in[6];
    const float* b2 = (const float*)d_in[7];

    const int N = in_sizes[0] / F_IN;   // 100000
    const int P = in_sizes[1] / 3;      // 1000000

    float* ws = (float*)d_ws;
    // workspace (float units): peak ~238N + P + 68k floats (~99.5 MB)
    size_t off_h1     = 0;                          // 64N  (bf16 x 128N)
    size_t off_d1     = (size_t)64 * N;             // 24N
    size_t off_elu    = (size_t)88 * N;             // 128N
    size_t off_h2     = (size_t)216 * N;            // 16N
    size_t off_d2     = (size_t)232 * N;            // 3N
    size_t off_deg    = (size_t)235 * N;            // N (int)
    size_t off_start  = (size_t)236 * N;            // N (int)
    size_t off_cursor = (size_t)237 * N;            // N (int)
    size_t off_gmax   = (size_t)238 * N;            // 32 (uint: 16 for d1, 2 for d2)
    size_t off_zpad   = (size_t)238 * N + 32;       // 64 (float, zeroed; 16B-aligned pad for gemm1 k>=500)
    size_t off_bsum   = (size_t)238 * N + 96;       // 1024 (int)
    size_t off_csr    = (size_t)238 * N + 96 + 1024; // P (int)
    size_t off_w1th   = off_csr + P;                // 32768 (bf16 x 65536)
    size_t off_w1tl   = off_w1th + 32768;           // 32768

    __hip_bfloat16* h1 = (__hip_bfloat16*)(ws + off_h1);
    float* d1   = ws + off_d1;
    float* elu  = ws + off_elu;
    float* h2   = ws + off_h2;
    float* d2   = ws + off_d2;
    int* deg    = (int*)(ws + off_deg);
    int* start  = (int*)(ws + off_start);
    int* cursor = (int*)(ws + off_cursor);
    unsigned int* gmax  = (unsigned int*)(ws + off_gmax);       // 16
    unsigned int* gmax2 = (unsigned int*)(ws + off_gmax) + 16;  // 2
    float* zpad = ws + off_zpad;
    int* bsum   = (int*)(ws + off_bsum);
    int* csr    = (int*)(ws + off_csr);
    __bf16* w1t_hi = (__bf16*)(ws + off_w1th);
    __bf16* w1t_lo = (__bf16*)(ws + off_w1tl);

    const int BLK = 256;
    const int nb = (N + 255) / 256;   // scan blocks (<= 512)
    const int nz = 3 * N + 96;        // deg..zpad zero region
    const int nprep = (HC * KPAD > nz ? HC * KPAD : nz);

    prep_kernel<<<(nprep + 255) / 256, 256, 0, stream>>>(W1, w1t_hi, w1t_lo, deg, nz);
    gemm1_v6<<<(N + 63) / 64, 256, 0, stream>>>(x, w1t_hi, w1t_lo, zpad, h1, N);
    dots1_kernel<<<(N * NHEAD + BLK - 1) / BLK, BLK, 0, stream>>>(h1, a1, d1, gmax, N);
    // CSR build
    hist_kernel<<<(P + BLK - 1) / BLK, BLK, 0, stream>>>(pi, deg, P);
    scan1_kernel<<<nb, 256, 0, stream>>>(deg, start, bsum, N);
    scan2_kernel<<<1, 512, 0, stream>>>(bsum, nb);
    scan3_kernel<<<nb, 256, 0, stream>>>(start, bsum, N);
    scatter_kernel<<<(P + BLK - 1) / BLK, BLK, 0, stream>>>(pi, start, cursor, csr, P);
    // layer 1 attention (single-pass, fused softmax/aggregate/bias/elu)
    attn1_csr_kernel<<<(N + 3) / 4, 256, 0, stream>>>(csr, start, deg, pi, d1, h1, b1, gmax, elu, N, P);
    // layer 2
    layer2_kernel<<<(N + 15) / 16, 256, 0, stream>>>(elu, W2, a2, h2, d2, gmax2, N);
    attn2_csr_kernel<<<(N + 15) / 16, 256, 0, stream>>>(csr, start, deg, pi, d2, h2, b2, gmax2,
                                                        (float*)d_out, N, P);
}

// Round 9
// 675.189 us; speedup vs baseline: 1.1440x; 1.0364x over previous
//
#include <hip/hip_runtime.h>
#include <hip/hip_bf16.h>

// Problem constants (shapes fixed by setup_inputs). All float I/O is fp32
// (established round 4: hardcoded-bf16 reads NaN'd twice; flag-version passed).
#define F_IN  500
#define HC    128   // H*C
#define NHEAD 8
#define CDIM  16
#define NCLS  16
#define KPAD  512   // F_IN padded to multiple of 32 for MFMA K-loop

static __device__ __forceinline__ float bf(const __hip_bfloat16 v) {
    return __bfloat162float(v);
}

// ordered-uint encoding for float atomicMax
static __device__ __forceinline__ unsigned int enc_f32(float f) {
    unsigned int u = __float_as_uint(f);
    return (u & 0x80000000u) ? ~u : (u | 0x80000000u);
}
static __device__ __forceinline__ float dec_f32(unsigned int u) {
    return __uint_as_float((u & 0x80000000u) ? (u & 0x7FFFFFFFu) : ~u);
}

typedef __bf16 bf16x8 __attribute__((ext_vector_type(8)));
typedef float f32x4 __attribute__((ext_vector_type(4)));

// async global->LDS, 16B per lane. LDS dest = wave-uniform base + lane*16.
static __device__ __forceinline__ void gload16(const void* g, void* l) {
    __builtin_amdgcn_global_load_lds(
        (const __attribute__((address_space(1))) void*)g,
        (__attribute__((address_space(3))) void*)l, 16, 0, 0);
}

// 32-bit LDS byte offset of a shared-memory pointer
static __device__ __forceinline__ unsigned ldsoff(const void* p) {
    return (unsigned)(size_t)(const __attribute__((address_space(3))) void*)p;
}

// opaque LDS read (invisible to the waitcnt pass; we do our own counted waits)
static __device__ __forceinline__ void ds_read_f4(unsigned addr, float4& out) {
    asm volatile("ds_read_b128 %0, %1" : "=v"(out) : "v"(addr) : "memory");
}

// opaque coalesced 16B global load with compile-time immediate offset
template<int OFF>
static __device__ __forceinline__ bf16x8 gld_b(const __bf16* p) {
    bf16x8 o;
    asm volatile("global_load_dwordx4 %0, %1, off offset:%2"
                 : "=v"(o) : "v"(p), "i"(OFF) : "memory");
    return o;
}

// ---------------------------------------------------------------- prep:
// W1 -> split-bf16 FRAGMENT-MAJOR layout (pure permutation of the 128x512
// transposed array; same 65536 elements, same workspace):
//   elem e = (((wc*16 + t)*4 + ct)*64 + lane)*8 + j
//   maps to col c = wc*64+ct*16+(lane&15), k = t*32+(lane>>4)*8+j.
// A wave's B-fragment load is then base+lane*16: perfectly coalesced 1KB.
// Also zeroes the int region (deg/start/cursor/gmax/zpad = 3N+96 ints).
__global__ void prep_kernel(const float* __restrict__ W1,
                            __bf16* __restrict__ w1t_hi,
                            __bf16* __restrict__ w1t_lo,
                            int* __restrict__ zp, int nz)
{
    int e = blockIdx.x * 256 + threadIdx.x;
    if (e < HC * KPAD) {
        int j = e & 7, lane = (e >> 3) & 63, ct = (e >> 9) & 3;
        int t = (e >> 11) & 15, wc = (e >> 15) & 1;
        int c = wc * 64 + ct * 16 + (lane & 15);
        int k = t * 32 + (lane >> 4) * 8 + j;
        float v = (k < F_IN) ? W1[k * HC + c] : 0.f;
        __bf16 h = (__bf16)v;
        w1t_hi[e] = h;
        w1t_lo[e] = (__bf16)(v - (float)h);
    }
    if (e < nz) zp[e] = 0;
}

// split 8 fp32 into bf16 hi + bf16 lo fragments
static __device__ __forceinline__ void split8(const float4 a, const float4 b,
                                              bf16x8& hi, bf16x8& lo) {
    float v[8] = {a.x, a.y, a.z, a.w, b.x, b.y, b.z, b.w};
#pragma unroll
    for (int j = 0; j < 8; j++) {
        __bf16 h = (__bf16)v[j];
        hi[j] = h;
        lo[j] = (__bf16)(v[j] - (float)h);
    }
}

// ---------------------------------------------------------------- GEMM1 v7 (MFMA, split-bf16):
// h1 = x @ W1 -> bf16 [N,128]. Block 64 rows x 128 cols, BK=32, 16 K-steps,
// 4 waves: wave (wr,wc) owns rows [wr*32,+32) x cols [wc*64,+64).
//  - B: fragment-major in global (L2-resident), loaded straight to registers
//    via coalesced inline-asm dwordx4, prefetched ONE step ahead. No LDS.
//  - A: global_load_lds into 4 x 8KB buffers, prefetched THREE steps ahead
//    (~1200cy >= 900cy HBM latency). Inline-asm ds_read fragments.
//  - All loop vmem is inline asm => vmcnt counting is exact. Per-iter issue
//    order [B(t+1):8, A(t+3):2]; steady wait vmcnt(12) completes exactly
//    {B(t), A(<=t+1)} (FIFO counter). Tail waits 10/8/0.
//  - launch_bounds(256,3): VGPR cap 170 > ~150 peak demand (64 B-dbuf + 32
//    acc + 16 fa + 16 ah/al + addressing) -> NO spills, 3 blocks/CU (12
//    waves/CU, +50% TLP vs (256,2)). (256,4)'s cap of 128 forced spills
//    whose scratch vmem broke the counted-vmcnt FIFO (R6/R7).
//  - Fused degree histogram in the epilogue (after vmcnt fully drains):
//    grid-stride atomicAdd over path heads -- hides under gemm1's latency
//    slack, removes the separate hist launch.
// MFMA order identical to v5/v6: acc += Ah*Bh + Ah*Bl + Al*Bh (bit-identical).
__global__ __launch_bounds__(256, 3) void gemm1_v7(
    const float* __restrict__ x,
    const __bf16* __restrict__ w1hi, const __bf16* __restrict__ w1lo,
    const float* __restrict__ zpad,
    __hip_bfloat16* __restrict__ h1,
    const int* __restrict__ pidx, int* __restrict__ deg, int N, int P)
{
    __shared__ float As[4][64 * 32];   // 32KB

    const int tid = threadIdx.x;
    const int lane = tid & 63, wave = tid >> 6;
    const int m = lane & 15, q = lane >> 4;
    const int wr = wave >> 1, wc = wave & 1;
    const int n0 = blockIdx.x * 64;
    const int woff = wave << 10;       // wave-uniform LDS byte offset

    // A stage: K-chunk t -> buffer buf (2 x global_load_lds per thread)
    auto stage = [&](int buf, int t) {
        const int k0 = t * 32;
#pragma unroll
        for (int j = 0; j < 2; ++j) {
            int idx = j * 256 + tid;
            int r = idx >> 3, ps = idx & 7;
            int ls = ps ^ (r & 7);
            int kk = k0 + ls * 4;
            int grow = n0 + r;
            const float* src = (kk < F_IN)
                ? (x + (size_t)(grow < N ? grow : 0) * F_IN + kk)
                : zpad;
            gload16(src, (char*)&As[buf][0] + j * 4096 + woff);
        }
    };

    // B per-lane fragment base (elems): wc-half + lane slot
    const __bf16* bh_base = w1hi + (size_t)wc * 32768 + (size_t)lane * 8;
    const __bf16* bl_base = w1lo + (size_t)wc * 32768 + (size_t)lane * 8;

    auto loadB = [&](bf16x8 (&bh)[4], bf16x8 (&bl)[4], int t) {
        const __bf16* ph = bh_base + (size_t)t * 2048;   // t*4096 bytes
        const __bf16* pl = bl_base + (size_t)t * 2048;
        bh[0] = gld_b<0>(ph);    bh[1] = gld_b<1024>(ph);
        bh[2] = gld_b<2048>(ph); bh[3] = gld_b<3072>(ph);
        bl[0] = gld_b<0>(pl);    bl[1] = gld_b<1024>(pl);
        bl[2] = gld_b<2048>(pl); bl[3] = gld_b<3072>(pl);
    };

    // LDS base offsets + per-lane A fragment offsets (row-swizzled 16B slots)
    unsigned abase[4];
#pragma unroll
    for (int i = 0; i < 4; ++i) abase[i] = ldsoff(&As[i][0]);
    unsigned aoffs[2][2];
#pragma unroll
    for (int rt = 0; rt < 2; ++rt) {
        int r = wr * 32 + rt * 16 + m, x7 = r & 7;
        aoffs[rt][0] = r * 128 + (((2 * q) ^ x7) << 4);
        aoffs[rt][1] = r * 128 + (((2 * q + 1) ^ x7) << 4);
    }

    f32x4 acc[2][4];
#pragma unroll
    for (int rt = 0; rt < 2; ++rt)
#pragma unroll
        for (int ct = 0; ct < 4; ++ct) acc[rt][ct] = (f32x4){0.f, 0.f, 0.f, 0.f};

    bf16x8 bhA[4], blA[4], bhB[4], blB[4];

    // prologue (issue order matters for FIFO vmcnt): A0, A1, B0, A2
    stage(0, 0);
    stage(1, 1);
    loadB(bhA, blA, 0);
    stage(2, 2);

    auto compute = [&](bf16x8 (&bh)[4], bf16x8 (&bl)[4],
                       bf16x8 (&ah)[2], bf16x8 (&al)[2]) {
        __builtin_amdgcn_s_setprio(1);
#pragma unroll
        for (int rt = 0; rt < 2; ++rt)
#pragma unroll
            for (int ct = 0; ct < 4; ++ct) {
                acc[rt][ct] = __builtin_amdgcn_mfma_f32_16x16x32_bf16(ah[rt], bh[ct], acc[rt][ct], 0, 0, 0);
                acc[rt][ct] = __builtin_amdgcn_mfma_f32_16x16x32_bf16(ah[rt], bl[ct], acc[rt][ct], 0, 0, 0);
                acc[rt][ct] = __builtin_amdgcn_mfma_f32_16x16x32_bf16(al[rt], bh[ct], acc[rt][ct], 0, 0, 0);
            }
        __builtin_amdgcn_s_setprio(0);
    };

#pragma unroll
    for (int t = 0; t < 16; ++t) {
        // top barrier: compute(t-1) ds_reads of buf (t-1)&3 done before
        // stage(t+3) DMA-writes the same buffer
        if (t > 0) __builtin_amdgcn_s_barrier();
        if (t + 1 < 16) {
            if ((t & 1) == 0) loadB(bhB, blB, t + 1);
            else              loadB(bhA, blA, t + 1);
        }
        if (t + 3 < 16) stage((t + 3) & 3, t + 3);

        // counted wait: completes exactly {B(t), A(<=t+1)} in FIFO order
        if (t <= 12)      asm volatile("s_waitcnt vmcnt(12)" ::: "memory");
        else if (t == 13) asm volatile("s_waitcnt vmcnt(10)" ::: "memory");
        else if (t == 14) asm volatile("s_waitcnt vmcnt(8)" ::: "memory");
        else              asm volatile("s_waitcnt vmcnt(0)" ::: "memory");
        __builtin_amdgcn_s_barrier();   // all waves' A(t) DMA visible

        const int cur = t & 3;
        float4 fa[2][2];
        ds_read_f4(abase[cur] + aoffs[0][0], fa[0][0]);
        ds_read_f4(abase[cur] + aoffs[0][1], fa[0][1]);
        ds_read_f4(abase[cur] + aoffs[1][0], fa[1][0]);
        ds_read_f4(abase[cur] + aoffs[1][1], fa[1][1]);
        asm volatile("s_waitcnt lgkmcnt(0)" ::: "memory");
        __builtin_amdgcn_sched_barrier(0);   // rule #18: pin uses after waits

        bf16x8 ah[2], al[2];
        split8(fa[0][0], fa[0][1], ah[0], al[0]);
        split8(fa[1][0], fa[1][1], ah[1], al[1]);

        if ((t & 1) == 0) compute(bhA, blA, ah, al);
        else              compute(bhB, blB, ah, al);
    }

    // store: C/D layout col=lane&15, row=(lane>>4)*4+reg
#pragma unroll
    for (int rt = 0; rt < 2; ++rt) {
        int rbase = n0 + wr * 32 + rt * 16 + q * 4;
#pragma unroll
        for (int ct = 0; ct < 4; ++ct) {
            int col = wc * 64 + ct * 16 + m;
#pragma unroll
            for (int r = 0; r < 4; ++r) {
                int row = rbase + r;
                if (row < N)
                    h1[(size_t)row * HC + col] = __float2bfloat16(acc[rt][ct][r]);
            }
        }
    }

    // fused degree histogram (plain compiler-tracked code; pipeline fully
    // drained at t=15's vmcnt(0), so no interaction with the asm discipline)
    const int gsz = gridDim.x * 256;
    for (int i = blockIdx.x * 256 + tid; i < P; i += gsz)
        atomicAdd(deg + pidx[i], 1);
}

// ---------------------------------------------------------------- per-node attention dots for layer 1
// d1[j*N*8 + n*8 + h] = sum_c h1[n,h,c] * a1[j,h,c]; fused per-head global max
// of d1m/d1t (replaces maxred_d1). h1 row read vectorized (2x bf16x8).
__global__ void dots1_kernel(const __hip_bfloat16* __restrict__ h1,
                             const float* __restrict__ a1,
                             float* __restrict__ d1,
                             unsigned int* __restrict__ gmax, int N)
{
    __shared__ unsigned int sm[16];
    if (threadIdx.x < 16) sm[threadIdx.x] = 0;
    __syncthreads();
    int id = blockIdx.x * blockDim.x + threadIdx.x;
    if (id < N * NHEAD) {
        int n = id >> 3, h = id & 7;
        const __hip_bfloat16* hp = h1 + (size_t)n * HC + h * CDIM;
        bf16x8 v0 = *(const bf16x8*)hp;
        bf16x8 v1 = *(const bf16x8*)(hp + 8);
        float s0 = 0.f, s1 = 0.f, s2 = 0.f;
#pragma unroll
        for (int c = 0; c < CDIM; c++) {
            float v = (c < 8) ? (float)v0[c & 7] : (float)v1[c & 7];
            s0 += v * a1[(0 * NHEAD + h) * CDIM + c];
            s1 += v * a1[(1 * NHEAD + h) * CDIM + c];
            s2 += v * a1[(2 * NHEAD + h) * CDIM + c];
        }
        d1[id] = s0;
        d1[N * NHEAD + id] = s1;
        d1[2 * N * NHEAD + id] = s2;
        atomicMax(&sm[h], enc_f32(s1));
        atomicMax(&sm[8 + h], enc_f32(s2));
    }
    __syncthreads();
    if (threadIdx.x < 16) atomicMax(&gmax[threadIdx.x], sm[threadIdx.x]);
}

// ---------------------------------------------------------------- CSR build
__global__ void scan1_kernel(const int* __restrict__ deg, int* __restrict__ start,
                             int* __restrict__ bsum, int N) {
    __shared__ int sh[256];
    int i = blockIdx.x * 256 + threadIdx.x;
    int v = (i < N) ? deg[i] : 0;
    sh[threadIdx.x] = v;
    __syncthreads();
#pragma unroll
    for (int off = 1; off < 256; off <<= 1) {
        int x = (threadIdx.x >= off) ? sh[threadIdx.x - off] : 0;
        __syncthreads();
        sh[threadIdx.x] += x;
        __syncthreads();
    }
    if (i < N) start[i] = sh[threadIdx.x] - v;   // exclusive
    if (threadIdx.x == 255) bsum[blockIdx.x] = sh[255];
}

__global__ void scan2_kernel(int* __restrict__ bsum, int nb) {
    __shared__ int sh[512];
    int v = (threadIdx.x < nb) ? bsum[threadIdx.x] : 0;
    sh[threadIdx.x] = v;
    __syncthreads();
#pragma unroll
    for (int off = 1; off < 512; off <<= 1) {
        int x = (threadIdx.x >= off) ? sh[threadIdx.x - off] : 0;
        __syncthreads();
        sh[threadIdx.x] += x;
        __syncthreads();
    }
    if (threadIdx.x < nb) bsum[threadIdx.x] = sh[threadIdx.x] - v;  // exclusive
}

__global__ void scan3_kernel(int* __restrict__ start, const int* __restrict__ bsum, int N) {
    int i = blockIdx.x * 256 + threadIdx.x;
    if (i < N) start[i] += bsum[blockIdx.x];
}

__global__ void scatter_kernel(const int* __restrict__ pidx,
                               const int* __restrict__ start,
                               int* __restrict__ cursor,
                               int* __restrict__ csr, int P) {
    int p = blockIdx.x * blockDim.x + threadIdx.x;
    if (p >= P) return;
    int hd = pidx[p];
    int pos = atomicAdd(cursor + hd, 1);
    csr[start[hd] + pos] = p;
}

// ---------------------------------------------------------------- layer1 attention, CSR, single pass.
// One wave per node. Softmax shift = upper bound leaky(dh + gm[h] + gt[h]).
// Hoisted inner gather (proven R8): per 8-path group, all 8 h1-row gathers
// issue into registers (independent loads in flight) before the FMA chain.
// Padded slots clamp to path dg-1 (same row as last valid slot; ~no extra
// traffic) and contribute exact +0.0f in the same dk positions.
__global__ __launch_bounds__(256) void attn1_csr_kernel(
    const int* __restrict__ csr, const int* __restrict__ start,
    const int* __restrict__ deg, const int* __restrict__ pidx,
    const float* __restrict__ d1, const __hip_bfloat16* __restrict__ h1,
    const float* __restrict__ b1, const unsigned int* __restrict__ gmax,
    float* __restrict__ elu_out, int N, int P)
{
    int node = blockIdx.x * 4 + (threadIdx.x >> 6);
    if (node >= N) return;
    int lane = threadIdx.x & 63;
    int h = lane >> 3;
    int s0 = start[node], dg = deg[node];
    const float* d1m = d1 + (size_t)N * NHEAD;
    const float* d1t = d1 + (size_t)2 * N * NHEAD;
    const float dh = d1[node * NHEAD + h];
    float zub = dh + dec_f32(gmax[h]) + dec_f32(gmax[8 + h]);
    const float mxub = zub > 0.f ? zub : 0.2f * zub;

    float acc0 = 0.f, acc1 = 0.f, den = 0.f;
    for (int k0 = 0; k0 < dg; k0 += 8) {
        int kk = k0 + (lane & 7);
        bool valid = kk < dg;
        int p = csr[s0 + (valid ? kk : dg - 1)];
        int mid = pidx[P + p], tl = pidx[2 * P + p];
        float z = dh + d1m[mid * NHEAD + h] + d1t[tl * NHEAD + h];
        float e = z > 0.f ? z : 0.2f * z;
        float ex = valid ? __expf(e - mxub) : 0.f;
        den += ex;
        // hoisted gather: 8 independent row loads in flight
        __hip_bfloat162 v[8];
        float exs[8];
#pragma unroll
        for (int dk = 0; dk < 8; dk++) {
            int tl_b = __shfl(tl, dk, 8);
            exs[dk] = __shfl(ex, dk, 8);
            v[dk] = *(const __hip_bfloat162*)(h1 + (size_t)tl_b * HC + 2 * lane);
        }
#pragma unroll
        for (int dk = 0; dk < 8; dk++) {
            acc0 += exs[dk] * bf(v[dk].x);
            acc1 += exs[dk] * bf(v[dk].y);
        }
    }
#pragma unroll
    for (int w = 1; w < 8; w <<= 1) den += __shfl_xor(den, w, 8);

    float inv = 1.f / (den + 1e-16f);
    int j0 = 2 * lane;
    float v0 = acc0 * inv + b1[j0];
    float v1 = acc1 * inv + b1[j0 + 1];
    v0 = v0 > 0.f ? v0 : __expf(v0) - 1.f;
    v1 = v1 > 0.f ? v1 : __expf(v1) - 1.f;
    *(float2*)(elu_out + (size_t)node * HC + j0) = make_float2(v0, v1);
}

// ---------------------------------------------------------------- layer2 GEMM + dots: h2 = elu @ W2 ; d2[j,n] = h2[n,:]·a2[j]
// fused global max of d2m/d2t (replaces maxred_d2)
__global__ __launch_bounds__(256) void layer2_kernel(
    const float* __restrict__ elu, const float* __restrict__ W2,
    const float* __restrict__ a2,
    float* __restrict__ h2, float* __restrict__ d2,
    unsigned int* __restrict__ gmax2, int N)
{
    __shared__ float rows[16][HC + 1];
    __shared__ float h2s[16][NCLS + 1];
    __shared__ unsigned int smax[2];
    const int n0 = blockIdx.x * 16;
    const int tid = threadIdx.x;
    if (tid < 2) smax[tid] = 0;
    for (int idx = tid; idx < 16 * HC; idx += 256) {
        int r = idx >> 7, c = idx & 127;
        rows[r][c] = (n0 + r < N) ? elu[(size_t)(n0 + r) * HC + c] : 0.f;
    }
    __syncthreads();
    int ln = tid >> 4, c = tid & 15;
    float acc = 0.f;
#pragma unroll 8
    for (int j = 0; j < HC; j++) acc += rows[ln][j] * W2[j * NCLS + c];
    h2s[ln][c] = acc;
    if (n0 + ln < N) h2[(size_t)(n0 + ln) * NCLS + c] = acc;
    __syncthreads();
    if (tid < 48) {
        int l = tid / 3, j = tid - l * 3;
        if (n0 + l < N) {
            float s = 0.f;
#pragma unroll
            for (int cc = 0; cc < NCLS; cc++) s += h2s[l][cc] * a2[j * NCLS + cc];
            d2[j * N + n0 + l] = s;
            if (j) atomicMax(&smax[j - 1], enc_f32(s));
        }
    }
    __syncthreads();
    if (tid < 2) atomicMax(&gmax2[tid], smax[tid]);
}

// ---------------------------------------------------------------- layer2 attention CSR, single pass + log_softmax -> out (fp32)
// Same hoisted-gather restructure (16-deep, fp32 rows).
__global__ __launch_bounds__(256) void attn2_csr_kernel(
    const int* __restrict__ csr, const int* __restrict__ start,
    const int* __restrict__ deg, const int* __restrict__ pidx,
    const float* __restrict__ d2, const float* __restrict__ h2,
    const float* __restrict__ b2, const unsigned int* __restrict__ gmax2,
    float* __restrict__ out, int N, int P)
{
    int node = blockIdx.x * 16 + (threadIdx.x >> 4);
    if (node >= N) return;
    int c = threadIdx.x & 15;
    int s0 = start[node], dg = deg[node];
    const float dh = d2[node];
    const float* d2m = d2 + N;
    const float* d2t = d2 + 2 * N;
    float zub = dh + dec_f32(gmax2[0]) + dec_f32(gmax2[1]);
    const float mxub = zub > 0.f ? zub : 0.2f * zub;

    float acc = 0.f, den = 0.f;
    for (int k0 = 0; k0 < dg; k0 += 16) {
        int kk = k0 + c;
        bool valid = kk < dg;
        int p = csr[s0 + (valid ? kk : dg - 1)];
        int mid = pidx[P + p], tl = pidx[2 * P + p];
        float z = dh + d2m[mid] + d2t[tl];
        float e = z > 0.f ? z : 0.2f * z;
        float ex = valid ? __expf(e - mxub) : 0.f;
        den += ex;
        // hoisted gather: 16 independent loads in flight
        float vv[16], exs[16];
#pragma unroll
        for (int dk = 0; dk < 16; dk++) {
            int tl_b = __shfl(tl, dk, 16);
            exs[dk] = __shfl(ex, dk, 16);
            vv[dk] = h2[(size_t)tl_b * NCLS + c];
        }
#pragma unroll
        for (int dk = 0; dk < 16; dk++) acc += exs[dk] * vv[dk];
    }
#pragma unroll
    for (int w = 1; w < 16; w <<= 1) den += __shfl_xor(den, w, 16);

    float o = acc / (den + 1e-16f) + b2[c];
    // log_softmax across the 16 lanes of this node
    float m2 = o;
#pragma unroll
    for (int w = 1; w < 16; w <<= 1) m2 = fmaxf(m2, __shfl_xor(m2, w, 16));
    float ex = __expf(o - m2), sm = ex;
#pragma unroll
    for (int w = 1; w < 16; w <<= 1) sm += __shfl_xor(sm, w, 16);
    float r = o - m2 - __logf(sm);
    out[(size_t)node * NCLS + c] = r;
}

// ================================================================ launch
extern "C" void kernel_launch(void* const* d_in, const int* in_sizes, int n_in,
                              void* d_out, int out_size, void* d_ws, size_t ws_size,
                              hipStream_t stream)
{
    const float* x  = (const float*)d_in[0];
    const int*   pi = (const int*)d_in[1];
    const float* W1 = (const float*)d_in[2];
    const float* a1 = (const float*)d_in[3];
    const float* b1 = (const float*)d_in[4];
    const float* W2 = (const float*)d_in[5];
    const float* a2 = (const float*)d_in[6];
    const float* b2 = (const float*)d_in[7];

    const int N = in_sizes[0] / F_IN;   // 100000
    const int P = in_sizes[1] / 3;      // 1000000

    float* ws = (float*)d_ws;
    // workspace (float units): peak ~238N + P + 68k floats (~99.5 MB)
    size_t off_h1     = 0;                          // 64N  (bf16 x 128N)
    size_t off_d1     = (size_t)64 * N;             // 24N
    size_t off_elu    = (size_t)88 * N;             // 128N
    size_t off_h2     = (size_t)216 * N;            // 16N
    size_t off_d2     = (size_t)232 * N;            // 3N
    size_t off_deg    = (size_t)235 * N;            // N (int)
    size_t off_start  = (size_t)236 * N;            // N (int)
    size_t off_cursor = (size_t)237 * N;            // N (int)
    size_t off_gmax   = (size_t)238 * N;            // 32 (uint: 16 for d1, 2 for d2)
    size_t off_zpad   = (size_t)238 * N + 32;       // 64 (float, zeroed; 16B-aligned pad for gemm1 k>=500)
    size_t off_bsum   = (size_t)238 * N + 96;       // 1024 (int)
    size_t off_csr    = (size_t)238 * N + 96 + 1024; // P (int)
    size_t off_w1th   = off_csr + P;                // 32768 (bf16 x 65536)
    size_t off_w1tl   = off_w1th + 32768;           // 32768

    __hip_bfloat16* h1 = (__hip_bfloat16*)(ws + off_h1);
    float* d1   = ws + off_d1;
    float* elu  = ws + off_elu;
    float* h2   = ws + off_h2;
    float* d2   = ws + off_d2;
    int* deg    = (int*)(ws + off_deg);
    int* start  = (int*)(ws + off_start);
    int* cursor = (int*)(ws + off_cursor);
    unsigned int* gmax  = (unsigned int*)(ws + off_gmax);       // 16
    unsigned int* gmax2 = (unsigned int*)(ws + off_gmax) + 16;  // 2
    float* zpad = ws + off_zpad;
    int* bsum   = (int*)(ws + off_bsum);
    int* csr    = (int*)(ws + off_csr);
    __bf16* w1t_hi = (__bf16*)(ws + off_w1th);
    __bf16* w1t_lo = (__bf16*)(ws + off_w1tl);

    const int BLK = 256;
    const int nb = (N + 255) / 256;   // scan blocks (<= 512)
    const int nz = 3 * N + 96;        // deg..zpad zero region
    const int nprep = (HC * KPAD > nz ? HC * KPAD : nz);

    prep_kernel<<<(nprep + 255) / 256, 256, 0, stream>>>(W1, w1t_hi, w1t_lo, deg, nz);
    gemm1_v7<<<(N + 63) / 64, 256, 0, stream>>>(x, w1t_hi, w1t_lo, zpad, h1, pi, deg, N, P);
    dots1_kernel<<<(N * NHEAD + BLK - 1) / BLK, BLK, 0, stream>>>(h1, a1, d1, gmax, N);
    // CSR build (hist fused into gemm1 epilogue)
    scan1_kernel<<<nb, 256, 0, stream>>>(deg, start, bsum, N);
    scan2_kernel<<<1, 512, 0, stream>>>(bsum, nb);
    scan3_kernel<<<nb, 256, 0, stream>>>(start, bsum, N);
    scatter_kernel<<<(P + BLK - 1) / BLK, BLK, 0, stream>>>(pi, start, cursor, csr, P);
    // layer 1 attention (single-pass, fused softmax/aggregate/bias/elu)
    attn1_csr_kernel<<<(N + 3) / 4, 256, 0, stream>>>(csr, start, deg, pi, d1, h1, b1, gmax, elu, N, P);
    // layer 2
    layer2_kernel<<<(N + 15) / 16, 256, 0, stream>>>(elu, W2, a2, h2, d2, gmax2, N);
    attn2_csr_kernel<<<(N + 15) / 16, 256, 0, stream>>>(csr, start, deg, pi, d2, h2, b2, gmax2,
                                                        (float*)d_out, N, P);
}

// Round 10
// 611.495 us; speedup vs baseline: 1.2632x; 1.1042x over previous
//
#include <hip/hip_runtime.h>
#include <hip/hip_bf16.h>

// Problem constants (shapes fixed by setup_inputs). All float I/O is fp32
// (established round 4: hardcoded-bf16 reads NaN'd twice; flag-version passed).
#define F_IN  500
#define HC    128   // H*C
#define NHEAD 8
#define CDIM  16
#define NCLS  16
#define KPAD  512   // F_IN padded to multiple of 32 for MFMA K-loop

static __device__ __forceinline__ float bf(const __hip_bfloat16 v) {
    return __bfloat162float(v);
}

// ordered-uint encoding for float atomicMax
static __device__ __forceinline__ unsigned int enc_f32(float f) {
    unsigned int u = __float_as_uint(f);
    return (u & 0x80000000u) ? ~u : (u | 0x80000000u);
}
static __device__ __forceinline__ float dec_f32(unsigned int u) {
    return __uint_as_float((u & 0x80000000u) ? (u & 0x7FFFFFFFu) : ~u);
}

typedef __bf16 bf16x8 __attribute__((ext_vector_type(8)));
typedef float f32x4 __attribute__((ext_vector_type(4)));

// async global->LDS, 16B per lane. LDS dest = wave-uniform base + lane*16.
static __device__ __forceinline__ void gload16(const void* g, void* l) {
    __builtin_amdgcn_global_load_lds(
        (const __attribute__((address_space(1))) void*)g,
        (__attribute__((address_space(3))) void*)l, 16, 0, 0);
}

// 32-bit LDS byte offset of a shared-memory pointer
static __device__ __forceinline__ unsigned ldsoff(const void* p) {
    return (unsigned)(size_t)(const __attribute__((address_space(3))) void*)p;
}

// opaque LDS read (invisible to the waitcnt pass; we do our own counted waits)
static __device__ __forceinline__ void ds_read_f4(unsigned addr, float4& out) {
    asm volatile("ds_read_b128 %0, %1" : "=v"(out) : "v"(addr) : "memory");
}

// opaque coalesced 16B global load with compile-time immediate offset
template<int OFF>
static __device__ __forceinline__ bf16x8 gld_b(const __bf16* p) {
    bf16x8 o;
    asm volatile("global_load_dwordx4 %0, %1, off offset:%2"
                 : "=v"(o) : "v"(p), "i"(OFF) : "memory");
    return o;
}

// ---------------------------------------------------------------- prep:
// W1 -> split-bf16 FRAGMENT-MAJOR layout (pure permutation of the 128x512
// transposed array; same 65536 elements, same workspace):
//   elem e = (((wc*16 + t)*4 + ct)*64 + lane)*8 + j
//   maps to col c = wc*64+ct*16+(lane&15), k = t*32+(lane>>4)*8+j.
// A wave's B-fragment load is then base+lane*16: perfectly coalesced 1KB.
// Also zeroes the int region (deg/start/cursor/gmax/zpad = 3N+96 ints).
__global__ void prep_kernel(const float* __restrict__ W1,
                            __bf16* __restrict__ w1t_hi,
                            __bf16* __restrict__ w1t_lo,
                            int* __restrict__ zp, int nz)
{
    int e = blockIdx.x * 256 + threadIdx.x;
    if (e < HC * KPAD) {
        int j = e & 7, lane = (e >> 3) & 63, ct = (e >> 9) & 3;
        int t = (e >> 11) & 15, wc = (e >> 15) & 1;
        int c = wc * 64 + ct * 16 + (lane & 15);
        int k = t * 32 + (lane >> 4) * 8 + j;
        float v = (k < F_IN) ? W1[k * HC + c] : 0.f;
        __bf16 h = (__bf16)v;
        w1t_hi[e] = h;
        w1t_lo[e] = (__bf16)(v - (float)h);
    }
    if (e < nz) zp[e] = 0;
}

// split 8 fp32 into bf16 hi + bf16 lo fragments
static __device__ __forceinline__ void split8(const float4 a, const float4 b,
                                              bf16x8& hi, bf16x8& lo) {
    float v[8] = {a.x, a.y, a.z, a.w, b.x, b.y, b.z, b.w};
#pragma unroll
    for (int j = 0; j < 8; j++) {
        __bf16 h = (__bf16)v[j];
        hi[j] = h;
        lo[j] = (__bf16)(v[j] - (float)h);
    }
}

// ---------------------------------------------------------------- GEMM1 v8 (MFMA, split-bf16):
// h1 = x @ W1 -> bf16 [N,128]. Identical K-loop to v7 (proven R9):
// 64x128 block, BK=32, 16 steps; B fragment-major direct-to-reg (1-step
// prefetch); A via global_load_lds into 4 buffers (3-step prefetch);
// inline-asm vmem + exact counted vmcnt(12/10/8/0); launch_bounds(256,3).
// NEW in v8 (epilogue only, after the pipeline fully drains):
//  - fused dots1: each wave holds h1 tile in acc; head h = wc*4+ct,
//    channel c = m, row = n0+wr*32+rt*16+q*4+r. d1[j] = sum_m v*a1[j][h][m]
//    via 16-lane shfl_xor reduce. v is acc round-tripped through bf16 so
//    d1 numerics EXACTLY match the old dots1-reads-h1 path.
//  - fused per-head gmax of d1m/d1t (block smem + one global atomicMax).
//  - fused degree histogram (carried from v7).
__global__ __launch_bounds__(256, 3) void gemm1_v8(
    const float* __restrict__ x,
    const __bf16* __restrict__ w1hi, const __bf16* __restrict__ w1lo,
    const float* __restrict__ zpad,
    __hip_bfloat16* __restrict__ h1,
    const float* __restrict__ a1, float* __restrict__ d1,
    unsigned int* __restrict__ gmax,
    const int* __restrict__ pidx, int* __restrict__ deg, int N, int P)
{
    __shared__ float As[4][64 * 32];   // 32KB
    __shared__ unsigned int smax[16];

    const int tid = threadIdx.x;
    const int lane = tid & 63, wave = tid >> 6;
    const int m = lane & 15, q = lane >> 4;
    const int wr = wave >> 1, wc = wave & 1;
    const int n0 = blockIdx.x * 64;
    const int woff = wave << 10;       // wave-uniform LDS byte offset

    if (tid < 16) smax[tid] = 0;       // visible by the t=0 barrier

    // A stage: K-chunk t -> buffer buf (2 x global_load_lds per thread)
    auto stage = [&](int buf, int t) {
        const int k0 = t * 32;
#pragma unroll
        for (int j = 0; j < 2; ++j) {
            int idx = j * 256 + tid;
            int r = idx >> 3, ps = idx & 7;
            int ls = ps ^ (r & 7);
            int kk = k0 + ls * 4;
            int grow = n0 + r;
            const float* src = (kk < F_IN)
                ? (x + (size_t)(grow < N ? grow : 0) * F_IN + kk)
                : zpad;
            gload16(src, (char*)&As[buf][0] + j * 4096 + woff);
        }
    };

    // B per-lane fragment base (elems): wc-half + lane slot
    const __bf16* bh_base = w1hi + (size_t)wc * 32768 + (size_t)lane * 8;
    const __bf16* bl_base = w1lo + (size_t)wc * 32768 + (size_t)lane * 8;

    auto loadB = [&](bf16x8 (&bh)[4], bf16x8 (&bl)[4], int t) {
        const __bf16* ph = bh_base + (size_t)t * 2048;   // t*4096 bytes
        const __bf16* pl = bl_base + (size_t)t * 2048;
        bh[0] = gld_b<0>(ph);    bh[1] = gld_b<1024>(ph);
        bh[2] = gld_b<2048>(ph); bh[3] = gld_b<3072>(ph);
        bl[0] = gld_b<0>(pl);    bl[1] = gld_b<1024>(pl);
        bl[2] = gld_b<2048>(pl); bl[3] = gld_b<3072>(pl);
    };

    // LDS base offsets + per-lane A fragment offsets (row-swizzled 16B slots)
    unsigned abase[4];
#pragma unroll
    for (int i = 0; i < 4; ++i) abase[i] = ldsoff(&As[i][0]);
    unsigned aoffs[2][2];
#pragma unroll
    for (int rt = 0; rt < 2; ++rt) {
        int r = wr * 32 + rt * 16 + m, x7 = r & 7;
        aoffs[rt][0] = r * 128 + (((2 * q) ^ x7) << 4);
        aoffs[rt][1] = r * 128 + (((2 * q + 1) ^ x7) << 4);
    }

    f32x4 acc[2][4];
#pragma unroll
    for (int rt = 0; rt < 2; ++rt)
#pragma unroll
        for (int ct = 0; ct < 4; ++ct) acc[rt][ct] = (f32x4){0.f, 0.f, 0.f, 0.f};

    bf16x8 bhA[4], blA[4], bhB[4], blB[4];

    // prologue (issue order matters for FIFO vmcnt): A0, A1, B0, A2
    stage(0, 0);
    stage(1, 1);
    loadB(bhA, blA, 0);
    stage(2, 2);

    auto compute = [&](bf16x8 (&bh)[4], bf16x8 (&bl)[4],
                       bf16x8 (&ah)[2], bf16x8 (&al)[2]) {
        __builtin_amdgcn_s_setprio(1);
#pragma unroll
        for (int rt = 0; rt < 2; ++rt)
#pragma unroll
            for (int ct = 0; ct < 4; ++ct) {
                acc[rt][ct] = __builtin_amdgcn_mfma_f32_16x16x32_bf16(ah[rt], bh[ct], acc[rt][ct], 0, 0, 0);
                acc[rt][ct] = __builtin_amdgcn_mfma_f32_16x16x32_bf16(ah[rt], bl[ct], acc[rt][ct], 0, 0, 0);
                acc[rt][ct] = __builtin_amdgcn_mfma_f32_16x16x32_bf16(al[rt], bh[ct], acc[rt][ct], 0, 0, 0);
            }
        __builtin_amdgcn_s_setprio(0);
    };

#pragma unroll
    for (int t = 0; t < 16; ++t) {
        // top barrier: compute(t-1) ds_reads of buf (t-1)&3 done before
        // stage(t+3) DMA-writes the same buffer
        if (t > 0) __builtin_amdgcn_s_barrier();
        if (t + 1 < 16) {
            if ((t & 1) == 0) loadB(bhB, blB, t + 1);
            else              loadB(bhA, blA, t + 1);
        }
        if (t + 3 < 16) stage((t + 3) & 3, t + 3);

        // counted wait: completes exactly {B(t), A(<=t+1)} in FIFO order
        if (t <= 12)      asm volatile("s_waitcnt vmcnt(12)" ::: "memory");
        else if (t == 13) asm volatile("s_waitcnt vmcnt(10)" ::: "memory");
        else if (t == 14) asm volatile("s_waitcnt vmcnt(8)" ::: "memory");
        else              asm volatile("s_waitcnt vmcnt(0)" ::: "memory");
        __builtin_amdgcn_s_barrier();   // all waves' A(t) DMA visible

        const int cur = t & 3;
        float4 fa[2][2];
        ds_read_f4(abase[cur] + aoffs[0][0], fa[0][0]);
        ds_read_f4(abase[cur] + aoffs[0][1], fa[0][1]);
        ds_read_f4(abase[cur] + aoffs[1][0], fa[1][0]);
        ds_read_f4(abase[cur] + aoffs[1][1], fa[1][1]);
        asm volatile("s_waitcnt lgkmcnt(0)" ::: "memory");
        __builtin_amdgcn_sched_barrier(0);   // rule #18: pin uses after waits

        bf16x8 ah[2], al[2];
        split8(fa[0][0], fa[0][1], ah[0], al[0]);
        split8(fa[1][0], fa[1][1], ah[1], al[1]);

        if ((t & 1) == 0) compute(bhA, blA, ah, al);
        else              compute(bhB, blB, ah, al);
    }

    // store: C/D layout col=lane&15, row=(lane>>4)*4+reg
#pragma unroll
    for (int rt = 0; rt < 2; ++rt) {
        int rbase = n0 + wr * 32 + rt * 16 + q * 4;
#pragma unroll
        for (int ct = 0; ct < 4; ++ct) {
            int col = wc * 64 + ct * 16 + m;
#pragma unroll
            for (int r = 0; r < 4; ++r) {
                int row = rbase + r;
                if (row < N)
                    h1[(size_t)row * HC + col] = __float2bfloat16(acc[rt][ct][r]);
            }
        }
    }

    // fused dots1: per (rt,ct,r) the 16 m-lanes of a q-group hold one h1 row
    // segment for head h = wc*4+ct. Reduce v*a1 over m; m==0 lane stores.
    // v = bf16-roundtrip(acc) => numerics identical to reading h1.
#pragma unroll
    for (int rt = 0; rt < 2; ++rt)
#pragma unroll
        for (int ct = 0; ct < 4; ++ct) {
            int h = wc * 4 + ct;
            float w0 = a1[(0 * NHEAD + h) * CDIM + m];
            float w1 = a1[(1 * NHEAD + h) * CDIM + m];
            float w2 = a1[(2 * NHEAD + h) * CDIM + m];
#pragma unroll
            for (int r = 0; r < 4; ++r) {
                float v = bf(__float2bfloat16(acc[rt][ct][r]));
                float s0 = v * w0, s1 = v * w1, s2 = v * w2;
#pragma unroll
                for (int w = 1; w < 16; w <<= 1) {
                    s0 += __shfl_xor(s0, w, 16);
                    s1 += __shfl_xor(s1, w, 16);
                    s2 += __shfl_xor(s2, w, 16);
                }
                int row = n0 + wr * 32 + rt * 16 + q * 4 + r;
                if (m == 0 && row < N) {
                    d1[(size_t)row * NHEAD + h] = s0;
                    d1[(size_t)N * NHEAD + (size_t)row * NHEAD + h] = s1;
                    d1[(size_t)2 * N * NHEAD + (size_t)row * NHEAD + h] = s2;
                    atomicMax(&smax[h], enc_f32(s1));
                    atomicMax(&smax[8 + h], enc_f32(s2));
                }
            }
        }
    __syncthreads();
    if (tid < 16) atomicMax(&gmax[tid], smax[tid]);

    // fused degree histogram (plain compiler-tracked code; pipeline fully
    // drained at t=15's vmcnt(0), so no interaction with the asm discipline)
    const int gsz = gridDim.x * 256;
    for (int i = blockIdx.x * 256 + tid; i < P; i += gsz)
        atomicAdd(deg + pidx[i], 1);
}

// ---------------------------------------------------------------- CSR build
__global__ void scan1_kernel(const int* __restrict__ deg, int* __restrict__ start,
                             int* __restrict__ bsum, int N) {
    __shared__ int sh[256];
    int i = blockIdx.x * 256 + threadIdx.x;
    int v = (i < N) ? deg[i] : 0;
    sh[threadIdx.x] = v;
    __syncthreads();
#pragma unroll
    for (int off = 1; off < 256; off <<= 1) {
        int x = (threadIdx.x >= off) ? sh[threadIdx.x - off] : 0;
        __syncthreads();
        sh[threadIdx.x] += x;
        __syncthreads();
    }
    if (i < N) start[i] = sh[threadIdx.x] - v;   // exclusive
    if (threadIdx.x == 255) bsum[blockIdx.x] = sh[255];
}

__global__ void scan2_kernel(int* __restrict__ bsum, int nb) {
    __shared__ int sh[512];
    int v = (threadIdx.x < nb) ? bsum[threadIdx.x] : 0;
    sh[threadIdx.x] = v;
    __syncthreads();
#pragma unroll
    for (int off = 1; off < 512; off <<= 1) {
        int x = (threadIdx.x >= off) ? sh[threadIdx.x - off] : 0;
        __syncthreads();
        sh[threadIdx.x] += x;
        __syncthreads();
    }
    if (threadIdx.x < nb) bsum[threadIdx.x] = sh[threadIdx.x] - v;  // exclusive
}

__global__ void scan3_kernel(int* __restrict__ start, const int* __restrict__ bsum, int N) {
    int i = blockIdx.x * 256 + threadIdx.x;
    if (i < N) start[i] += bsum[blockIdx.x];
}

__global__ void scatter_kernel(const int* __restrict__ pidx,
                               const int* __restrict__ start,
                               int* __restrict__ cursor,
                               int* __restrict__ csr, int P) {
    int p = blockIdx.x * blockDim.x + threadIdx.x;
    if (p >= P) return;
    int hd = pidx[p];
    int pos = atomicAdd(cursor + hd, 1);
    csr[start[hd] + pos] = p;
}

// ---------------------------------------------------------------- layer1 attention, CSR, single pass.
// One wave per node. Softmax shift = upper bound leaky(dh + gm[h] + gt[h]).
// Hoisted inner gather (proven R8): per 8-path group, all 8 h1-row gathers
// issue into registers (independent loads in flight) before the FMA chain.
// Padded slots clamp to path dg-1 (same row as last valid slot; ~no extra
// traffic) and contribute exact +0.0f in the same dk positions.
__global__ __launch_bounds__(256) void attn1_csr_kernel(
    const int* __restrict__ csr, const int* __restrict__ start,
    const int* __restrict__ deg, const int* __restrict__ pidx,
    const float* __restrict__ d1, const __hip_bfloat16* __restrict__ h1,
    const float* __restrict__ b1, const unsigned int* __restrict__ gmax,
    float* __restrict__ elu_out, int N, int P)
{
    int node = blockIdx.x * 4 + (threadIdx.x >> 6);
    if (node >= N) return;
    int lane = threadIdx.x & 63;
    int h = lane >> 3;
    int s0 = start[node], dg = deg[node];
    const float* d1m = d1 + (size_t)N * NHEAD;
    const float* d1t = d1 + (size_t)2 * N * NHEAD;
    const float dh = d1[node * NHEAD + h];
    float zub = dh + dec_f32(gmax[h]) + dec_f32(gmax[8 + h]);
    const float mxub = zub > 0.f ? zub : 0.2f * zub;

    float acc0 = 0.f, acc1 = 0.f, den = 0.f;
    for (int k0 = 0; k0 < dg; k0 += 8) {
        int kk = k0 + (lane & 7);
        bool valid = kk < dg;
        int p = csr[s0 + (valid ? kk : dg - 1)];
        int mid = pidx[P + p], tl = pidx[2 * P + p];
        float z = dh + d1m[mid * NHEAD + h] + d1t[tl * NHEAD + h];
        float e = z > 0.f ? z : 0.2f * z;
        float ex = valid ? __expf(e - mxub) : 0.f;
        den += ex;
        // hoisted gather: 8 independent row loads in flight
        __hip_bfloat162 v[8];
        float exs[8];
#pragma unroll
        for (int dk = 0; dk < 8; dk++) {
            int tl_b = __shfl(tl, dk, 8);
            exs[dk] = __shfl(ex, dk, 8);
            v[dk] = *(const __hip_bfloat162*)(h1 + (size_t)tl_b * HC + 2 * lane);
        }
#pragma unroll
        for (int dk = 0; dk < 8; dk++) {
            acc0 += exs[dk] * bf(v[dk].x);
            acc1 += exs[dk] * bf(v[dk].y);
        }
    }
#pragma unroll
    for (int w = 1; w < 8; w <<= 1) den += __shfl_xor(den, w, 8);

    float inv = 1.f / (den + 1e-16f);
    int j0 = 2 * lane;
    float v0 = acc0 * inv + b1[j0];
    float v1 = acc1 * inv + b1[j0 + 1];
    v0 = v0 > 0.f ? v0 : __expf(v0) - 1.f;
    v1 = v1 > 0.f ? v1 : __expf(v1) - 1.f;
    *(float2*)(elu_out + (size_t)node * HC + j0) = make_float2(v0, v1);
}

// ---------------------------------------------------------------- layer2 GEMM + dots: h2 = elu @ W2 ; d2[j,n] = h2[n,:]·a2[j]
// 64-row blocks (4x fewer blocks -> 4x less W2 re-read); float4 elu loads
// (pad HC+4 keeps 16B alignment of each row). Per-row math order unchanged.
// Fused global max of d2m/d2t.
__global__ __launch_bounds__(256) void layer2_kernel(
    const float* __restrict__ elu, const float* __restrict__ W2,
    const float* __restrict__ a2,
    float* __restrict__ h2, float* __restrict__ d2,
    unsigned int* __restrict__ gmax2, int N)
{
    __shared__ float rows[64][HC + 4];   // 33KB, rows 16B-aligned
    __shared__ float h2s[64][NCLS + 1];
    __shared__ unsigned int smax[2];
    const int n0 = blockIdx.x * 64;
    const int tid = threadIdx.x;
    if (tid < 2) smax[tid] = 0;
    for (int idx = tid; idx < 64 * 32; idx += 256) {   // 2048 float4
        int r = idx >> 5, c4 = idx & 31;
        float4 v = (n0 + r < N)
            ? *(const float4*)&elu[(size_t)(n0 + r) * HC + c4 * 4]
            : make_float4(0.f, 0.f, 0.f, 0.f);
        *(float4*)&rows[r][c4 * 4] = v;
    }
    __syncthreads();
    int ln = tid >> 4, c = tid & 15;
#pragma unroll
    for (int pass = 0; pass < 4; ++pass) {
        int r = pass * 16 + ln;
        float acc = 0.f;
#pragma unroll 8
        for (int j = 0; j < HC; j++) acc += rows[r][j] * W2[j * NCLS + c];
        h2s[r][c] = acc;
        if (n0 + r < N) h2[(size_t)(n0 + r) * NCLS + c] = acc;
    }
    __syncthreads();
    if (tid < 192) {
        int l = tid / 3, j = tid - l * 3;
        if (n0 + l < N) {
            float s = 0.f;
#pragma unroll
            for (int cc = 0; cc < NCLS; cc++) s += h2s[l][cc] * a2[j * NCLS + cc];
            d2[j * N + n0 + l] = s;
            if (j) atomicMax(&smax[j - 1], enc_f32(s));
        }
    }
    __syncthreads();
    if (tid < 2) atomicMax(&gmax2[tid], smax[tid]);
}

// ---------------------------------------------------------------- layer2 attention CSR, single pass + log_softmax -> out (fp32)
// Same hoisted-gather restructure (16-deep, fp32 rows).
__global__ __launch_bounds__(256) void attn2_csr_kernel(
    const int* __restrict__ csr, const int* __restrict__ start,
    const int* __restrict__ deg, const int* __restrict__ pidx,
    const float* __restrict__ d2, const float* __restrict__ h2,
    const float* __restrict__ b2, const unsigned int* __restrict__ gmax2,
    float* __restrict__ out, int N, int P)
{
    int node = blockIdx.x * 16 + (threadIdx.x >> 4);
    if (node >= N) return;
    int c = threadIdx.x & 15;
    int s0 = start[node], dg = deg[node];
    const float dh = d2[node];
    const float* d2m = d2 + N;
    const float* d2t = d2 + 2 * N;
    float zub = dh + dec_f32(gmax2[0]) + dec_f32(gmax2[1]);
    const float mxub = zub > 0.f ? zub : 0.2f * zub;

    float acc = 0.f, den = 0.f;
    for (int k0 = 0; k0 < dg; k0 += 16) {
        int kk = k0 + c;
        bool valid = kk < dg;
        int p = csr[s0 + (valid ? kk : dg - 1)];
        int mid = pidx[P + p], tl = pidx[2 * P + p];
        float z = dh + d2m[mid] + d2t[tl];
        float e = z > 0.f ? z : 0.2f * z;
        float ex = valid ? __expf(e - mxub) : 0.f;
        den += ex;
        // hoisted gather: 16 independent loads in flight
        float vv[16], exs[16];
#pragma unroll
        for (int dk = 0; dk < 16; dk++) {
            int tl_b = __shfl(tl, dk, 16);
            exs[dk] = __shfl(ex, dk, 16);
            vv[dk] = h2[(size_t)tl_b * NCLS + c];
        }
#pragma unroll
        for (int dk = 0; dk < 16; dk++) acc += exs[dk] * vv[dk];
    }
#pragma unroll
    for (int w = 1; w < 16; w <<= 1) den += __shfl_xor(den, w, 16);

    float o = acc / (den + 1e-16f) + b2[c];
    // log_softmax across the 16 lanes of this node
    float m2 = o;
#pragma unroll
    for (int w = 1; w < 16; w <<= 1) m2 = fmaxf(m2, __shfl_xor(m2, w, 16));
    float ex = __expf(o - m2), sm = ex;
#pragma unroll
    for (int w = 1; w < 16; w <<= 1) sm += __shfl_xor(sm, w, 16);
    float r = o - m2 - __logf(sm);
    out[(size_t)node * NCLS + c] = r;
}

// ================================================================ launch
extern "C" void kernel_launch(void* const* d_in, const int* in_sizes, int n_in,
                              void* d_out, int out_size, void* d_ws, size_t ws_size,
                              hipStream_t stream)
{
    const float* x  = (const float*)d_in[0];
    const int*   pi = (const int*)d_in[1];
    const float* W1 = (const float*)d_in[2];
    const float* a1 = (const float*)d_in[3];
    const float* b1 = (const float*)d_in[4];
    const float* W2 = (const float*)d_in[5];
    const float* a2 = (const float*)d_in[6];
    const float* b2 = (const float*)d_in[7];

    const int N = in_sizes[0] / F_IN;   // 100000
    const int P = in_sizes[1] / 3;      // 1000000

    float* ws = (float*)d_ws;
    // workspace (float units): peak ~238N + P + 68k floats (~99.5 MB)
    size_t off_h1     = 0;                          // 64N  (bf16 x 128N)
    size_t off_d1     = (size_t)64 * N;             // 24N
    size_t off_elu    = (size_t)88 * N;             // 128N
    size_t off_h2     = (size_t)216 * N;            // 16N
    size_t off_d2     = (size_t)232 * N;            // 3N
    size_t off_deg    = (size_t)235 * N;            // N (int)
    size_t off_start  = (size_t)236 * N;            // N (int)
    size_t off_cursor = (size_t)237 * N;            // N (int)
    size_t off_gmax   = (size_t)238 * N;            // 32 (uint: 16 for d1, 2 for d2)
    size_t off_zpad   = (size_t)238 * N + 32;       // 64 (float, zeroed; 16B-aligned pad for gemm1 k>=500)
    size_t off_bsum   = (size_t)238 * N + 96;       // 1024 (int)
    size_t off_csr    = (size_t)238 * N + 96 + 1024; // P (int)
    size_t off_w1th   = off_csr + P;                // 32768 (bf16 x 65536)
    size_t off_w1tl   = off_w1th + 32768;           // 32768

    __hip_bfloat16* h1 = (__hip_bfloat16*)(ws + off_h1);
    float* d1   = ws + off_d1;
    float* elu  = ws + off_elu;
    float* h2   = ws + off_h2;
    float* d2   = ws + off_d2;
    int* deg    = (int*)(ws + off_deg);
    int* start  = (int*)(ws + off_start);
    int* cursor = (int*)(ws + off_cursor);
    unsigned int* gmax  = (unsigned int*)(ws + off_gmax);       // 16
    unsigned int* gmax2 = (unsigned int*)(ws + off_gmax) + 16;  // 2
    float* zpad = ws + off_zpad;
    int* bsum   = (int*)(ws + off_bsum);
    int* csr    = (int*)(ws + off_csr);
    __bf16* w1t_hi = (__bf16*)(ws + off_w1th);
    __bf16* w1t_lo = (__bf16*)(ws + off_w1tl);

    const int BLK = 256;
    const int nb = (N + 255) / 256;   // scan blocks (<= 512)
    const int nz = 3 * N + 96;        // deg..zpad zero region
    const int nprep = (HC * KPAD > nz ? HC * KPAD : nz);

    prep_kernel<<<(nprep + 255) / 256, 256, 0, stream>>>(W1, w1t_hi, w1t_lo, deg, nz);
    gemm1_v8<<<(N + 63) / 64, 256, 0, stream>>>(x, w1t_hi, w1t_lo, zpad, h1,
                                                a1, d1, gmax, pi, deg, N, P);
    // CSR build (hist fused into gemm1 epilogue; dots1 fused too)
    scan1_kernel<<<nb, 256, 0, stream>>>(deg, start, bsum, N);
    scan2_kernel<<<1, 512, 0, stream>>>(bsum, nb);
    scan3_kernel<<<nb, 256, 0, stream>>>(start, bsum, N);
    scatter_kernel<<<(P + BLK - 1) / BLK, BLK, 0, stream>>>(pi, start, cursor, csr, P);
    // layer 1 attention (single-pass, fused softmax/aggregate/bias/elu)
    attn1_csr_kernel<<<(N + 3) / 4, 256, 0, stream>>>(csr, start, deg, pi, d1, h1, b1, gmax, elu, N, P);
    // layer 2
    layer2_kernel<<<(N + 63) / 64, 256, 0, stream>>>(elu, W2, a2, h2, d2, gmax2, N);
    attn2_csr_kernel<<<(N + 15) / 16, 256, 0, stream>>>(csr, start, deg, pi, d2, h2, b2, gmax2,
                                                        (float*)d_out, N, P);
}